// Round 3
// baseline (410.204 us; speedup 1.0000x reference)
//
#include <hip/hip_runtime.h>
#include <stdint.h>

#define B_ 8
#define S_ 1024
#define IN_DIM 512
#define DM 1024
#define H_ 16
#define DEP 64

typedef __bf16 bf16;
typedef __attribute__((ext_vector_type(8))) __bf16 bf16x8;
typedef __attribute__((ext_vector_type(4))) __bf16 bf16x4;
typedef __attribute__((ext_vector_type(4))) short short4v;
typedef __attribute__((ext_vector_type(4))) float f32x4;

// mfma 16x16x16 bf16: prefer gfx950-style name, fall back to CDNA2 _1k name.
#if defined(__has_builtin)
#if __has_builtin(__builtin_amdgcn_mfma_f32_16x16x16_bf16)
#define HAVE_NEW16 1
#endif
#endif
static __device__ __forceinline__ f32x4 mfma16(bf16x4 a, bf16x4 b, f32x4 c) {
#ifdef HAVE_NEW16
    return __builtin_amdgcn_mfma_f32_16x16x16_bf16(a, b, c, 0, 0, 0);
#else
    union { bf16x4 h; short4v s; } ua, ub;
    ua.h = a; ub.h = b;
    return __builtin_amdgcn_mfma_f32_16x16x16bf16_1k(ua.s, ub.s, c, 0, 0, 0);
#endif
}

// ---------------------------------------------------------------- async copy
static __device__ __forceinline__ void gld_lds16(const void* g, void* l) {
    __builtin_amdgcn_global_load_lds(
        (const __attribute__((address_space(1))) uint32_t*)g,
        (__attribute__((address_space(3))) uint32_t*)l, 16, 0, 0);
}

// ---------------------------------------------------------------- dtype detect
__global__ void detect_kernel(const uint16_t* __restrict__ xraw, int* __restrict__ flag) {
    const int t = threadIdx.x;  // 64 threads
    int sane = 0;
    #pragma unroll
    for (int j = 0; j < 8; j++) {
        const uint16_t u = xraw[t * 8 + j];
        const int e = (u >> 7) & 0xff;
        sane += ((u & 0x7fff) == 0 || (e >= 100 && e <= 140)) ? 1 : 0;
    }
    #pragma unroll
    for (int m = 1; m < 64; m <<= 1) sane += __shfl_xor(sane, m);
    if (t == 0) *flag = (sane >= 450) ? 1 : 0;
}

static __device__ __forceinline__ float ldin(const void* p, size_t i, int isb) {
    return isb ? (float)((const bf16*)p)[i] : ((const float*)p)[i];
}

// ---------------------------------------------------------------- weights -> bf16 [N][K]
__global__ __launch_bounds__(256) void transpose_kernel(
    const void* __restrict__ wq, const void* __restrict__ wk, const void* __restrict__ wv,
    const void* __restrict__ res, const void* __restrict__ dense,
    bf16* __restrict__ wqT, bf16* __restrict__ wkT, bf16* __restrict__ wvT,
    bf16* __restrict__ resT, bf16* __restrict__ denseT, const int* __restrict__ flag)
{
    const int isb = *flag;
    __shared__ bf16 tile[32][33];
    const int z = blockIdx.z;
    const void* src; bf16* dst; int kb, kd;
    if (z == 0)      { src = wq;    dst = wqT;    kb = 0;   kd = 512;  }
    else if (z == 1) { src = wk;    dst = wkT;    kb = 0;   kd = 512;  }
    else if (z == 2) { src = wv;    dst = wvT;    kb = 0;   kd = 512;  }
    else if (z == 3) { src = res;   dst = resT;   kb = 0;   kd = 512;  }
    else if (z == 4) { src = dense; dst = denseT; kb = 0;   kd = 1024; }
    else             { src = dense; dst = denseT; kb = 512; kd = 1024; }
    const int n0 = blockIdx.x * 32, k0 = blockIdx.y * 32;
    const int tx = threadIdx.x, ty = threadIdx.y;
    #pragma unroll
    for (int r = 0; r < 4; r++)
        tile[ty + r*8][tx] = (bf16)ldin(src, (size_t)(kb + k0 + ty + r*8) * DM + n0 + tx, isb);
    __syncthreads();
    #pragma unroll
    for (int r = 0; r < 4; r++)
        dst[(size_t)(n0 + ty + r*8) * kd + kb + k0 + tx] = tile[tx][ty + r*8];
}

// ---------------------------------------------------------------- x -> bf16
__global__ __launch_bounds__(256) void xconv_kernel(
    const void* __restrict__ x, bf16* __restrict__ xc, const int* __restrict__ flag)
{
    const int isb = *flag;
    const size_t i = ((size_t)blockIdx.x * 256 + threadIdx.x) * 4;
    #pragma unroll
    for (int j = 0; j < 4; j++) xc[i + j] = (bf16)ldin(x, i + j, isb);
}

// ---------------------------------------------------------------- small vectors -> bf16
// order: [wq_b, wk_b, wv_b, dense_b, ln_g, ln_b], each 1024
__global__ __launch_bounds__(256) void smallconv_kernel(
    const void* b0, const void* b1, const void* b2, const void* b3,
    const void* b4, const void* b5, bf16* __restrict__ out, const int* __restrict__ flag)
{
    const int isb = *flag;
    const void* srcs[6] = {b0, b1, b2, b3, b4, b5};
    const void* s = srcs[blockIdx.x];
    for (int i = threadIdx.x; i < 1024; i += 256)
        out[blockIdx.x * 1024 + i] = (bf16)ldin(s, i, isb);
}

// ---------------------------------------------------------------- mask -> bit pack (64 MB -> 2 MB)
__global__ __launch_bounds__(256) void maskpack_kernel(
    const int* __restrict__ mask, unsigned long long* __restrict__ mb)
{
    const int w = threadIdx.x >> 6, lane = threadIdx.x & 63;
    const int gw = blockIdx.x * 4 + w;           // 4096 waves
    for (int c = gw; c < 262144; c += 4096) {
        const int v = mask[(size_t)c * 64 + lane];
        const unsigned long long bits = __ballot(v != 0);
        if (lane == 0) mb[c] = bits;
    }
}

// ---------------------------------------------------------------- GEMM core 128x128 (async global->LDS, m97-style)
template<int KDIM>
static __device__ __forceinline__ void gemm_core(
    const bf16* __restrict__ A, const bf16* __restrict__ BT,
    int m0, int n0, bf16* Asm, bf16* Bsm, f32x4 acc[4][4])
{
    const int tid = threadIdx.x, l = tid & 63, w = tid >> 6;
    const int wm = w >> 1, wn = w & 1, quad = l >> 4, l15 = l & 15;
    #pragma unroll
    for (int i = 0; i < 4; i++)
        #pragma unroll
        for (int j = 0; j < 4; j++) acc[i][j] = f32x4{0.f, 0.f, 0.f, 0.f};

    for (int k0 = 0; k0 < KDIM; k0 += 32) {
        __syncthreads();
        #pragma unroll
        for (int qq = 0; qq < 2; qq++) {
            const int c = qq*256 + tid;
            const int row = c >> 2, ch = c & 3;      // [128 rows][4 chunks of 8 bf16]
            gld_lds16(A  + (size_t)(m0 + row)*KDIM + k0 + ch*8, Asm + (qq*256 + w*64)*8);
            gld_lds16(BT + (size_t)(n0 + row)*KDIM + k0 + ch*8, Bsm + (qq*256 + w*64)*8);
        }
        __syncthreads();
        bf16x8 af[4], bfv[4];
        #pragma unroll
        for (int i = 0; i < 4; i++)
            af[i] = *(const bf16x8*)(Asm + (wm*64 + i*16 + l15)*32 + quad*8);
        #pragma unroll
        for (int j = 0; j < 4; j++)
            bfv[j] = *(const bf16x8*)(Bsm + (wn*64 + j*16 + l15)*32 + quad*8);
        #pragma unroll
        for (int i = 0; i < 4; i++)
            #pragma unroll
            for (int j = 0; j < 4; j++)
                acc[i][j] = __builtin_amdgcn_mfma_f32_16x16x32_bf16(af[i], bfv[j], acc[i][j], 0, 0, 0);
    }
}

// ---------------------------------------------------------------- QKV + residual projection
// grid (64, 32). sel: 0=Q (scaled 0.125*log2(e) so attn can use raw v_exp_f32),
// 1=K, 2=V (written transposed [bh][d][s], k-PERMUTED within 32-blocks), 3=residual.
#define EPI_P 132
__global__ __launch_bounds__(256) void proj_kernel(
    const bf16* __restrict__ x,
    const bf16* __restrict__ wqT, const bf16* __restrict__ wkT,
    const bf16* __restrict__ wvT, const bf16* __restrict__ resT,
    const bf16* __restrict__ small,
    bf16* __restrict__ Q, bf16* __restrict__ K, bf16* __restrict__ VtG, bf16* __restrict__ R)
{
    __shared__ alignas(16) char smem[17408];   // union: staging (16384) | V-epilogue (16896)
    bf16* Asm = (bf16*)smem;
    bf16* Bsm = (bf16*)(smem + 8192);
    bf16* epi = (bf16*)smem;                   // [64 cols][EPI_P] rows-pitch

    const int m0 = blockIdx.x * 128;
    const int ng = blockIdx.y * 128;
    const int sel = ng >> 10, n0 = ng & 1023;
    const bf16* BT; const bf16* bias = nullptr;
    if (sel == 0)      { BT = wqT; bias = small;        }
    else if (sel == 1) { BT = wkT; bias = small + 1024; }
    else if (sel == 2) { BT = wvT; bias = small + 2048; }
    else               { BT = resT; }

    f32x4 acc[4][4];
    gemm_core<IN_DIM>(x, BT, m0, n0, Asm, Bsm, acc);

    const int tid = threadIdx.x, l = tid & 63, w = tid >> 6;
    const int wm = w >> 1, wn = w & 1, quad = l >> 4, l15 = l & 15;

    if (sel == 2) {
        // V: stage [col][row] in LDS, emit transposed VtG[(b*16+h)*64 + d][s'] coalesced.
        // s' is k-PERMUTED within each 32-block: position p holds source
        // kl = ((p&4)<<2) | ((p&24)>>1) | (p&3)   (i.e. p = quad*8 + h2*4 + r for
        // kl = h2*16 + quad*4 + r). This lets attn fetch both h2 fragments of a
        // (sub,quad) pair with ONE ds_read_b128, conflict-free under 8-lane phasing.
        const int bb = m0 >> 10, srow0 = m0 & 1023;
        #pragma unroll
        for (int hf = 0; hf < 2; hf++) {
            __syncthreads();
            if (wn == hf) {
                #pragma unroll
                for (int j = 0; j < 4; j++) {
                    const int cl = j*16 + l15;
                    const float bv = (float)bias[n0 + hf*64 + cl];
                    #pragma unroll
                    for (int i = 0; i < 4; i++) {
                        const int rho = wm*64 + i*16 + quad*4;
                        #pragma unroll
                        for (int r = 0; r < 4; r++)
                            epi[cl*EPI_P + rho + r] = (bf16)(acc[i][j][r] + bv);
                    }
                }
            }
            __syncthreads();
            const int hh = (n0 >> 6) + hf;
            const int sc = tid & 15;
            #pragma unroll
            for (int pass = 0; pass < 4; pass++) {
                const int dl = (tid >> 4) + pass*16;
                bf16x8 v;
                #pragma unroll
                for (int k = 0; k < 8; k++) {
                    const int pl = (sc & 3)*8 + k;                                  // pos in 32-block
                    const int kl = ((pl & 4) << 2) | ((pl & 24) >> 1) | (pl & 3);   // source pos
                    v[k] = epi[dl*EPI_P + (sc >> 2)*32 + kl];
                }
                *(bf16x8*)(VtG + ((size_t)(bb*16 + hh)*64 + dl)*S_ + srow0 + sc*8) = v;
            }
        }
        return;
    }

    #pragma unroll
    for (int j = 0; j < 4; j++) {
        const int col = n0 + wn*64 + j*16 + l15;
        const float bv = (sel < 3) ? (float)bias[col] : 0.f;
        #pragma unroll
        for (int i = 0; i < 4; i++) {
            const int rb = m0 + wm*64 + i*16 + quad*4;
            #pragma unroll
            for (int r = 0; r < 4; r++) {
                const float v = acc[i][j][r] + bv;
                // 0.125 * log2(e) = 0.18033688011112042: scores land in base-2 domain,
                // attn_kernel then uses raw v_exp_f32 (2^x) with no per-element multiply.
                if (sel == 0)      Q[(size_t)(rb + r)*DM + col] = (bf16)(v * 0.18033688f);
                else if (sel == 1) K[(size_t)(rb + r)*DM + col] = (bf16)v;
                else               R[(size_t)(rb + r)*DM + col] = (bf16)v;
            }
        }
    }
}

// ---------------------------------------------------------------- flash attention v7
// vs v6: V LDS tile now holds the k-permuted layout (from proj). A lane's two h2
// fragments for a (sub,quad) pair are 16B-contiguous -> ONE ds_read_b128 per
// (sub,dt) instead of two ds_read_b64. b128 phases are 8 lanes (8x16B = 128B/cy);
// each phase = fixed quad, 8 consecutive l15 -> 8 distinct XOR slots -> the 4.19M
// conflict cycles of v6's b64 va reads (16-lane phases, uniform quad&1 half-select,
// structural 2-way) go away. kf reads already conflict-free (same phasing argument).
// grid (8, 128): block = 128 q-rows of one (b,h); wave = 32 q-rows (2 groups of 16).
__global__ __launch_bounds__(256, 4) void attn_kernel(
    const bf16* __restrict__ Q, const bf16* __restrict__ K, const bf16* __restrict__ VtG,
    const unsigned long long* __restrict__ mb, bf16* __restrict__ AO)
{
    __shared__ alignas(16) bf16 Ksm[2*64*64];   // dbuf [krow][d], 16B-chunk XOR-swizzled
    __shared__ alignas(16) bf16 Vsm[2*64*64];   // dbuf [d][k-permuted], same swizzle

    const int tid = threadIdx.x, l = tid & 63, w = tid >> 6;
    const int quad = l >> 4, l15 = l & 15;

    // XCD swizzle: flat id f lands on XCD f%8 (round-robin dispatch). Remap so each
    // XCD owns 16 complete (b,h) groups incl. all 8 q-tiles (1024 % 8 == 0, bijective).
    const int fid = blockIdx.y * 8 + blockIdx.x;
    const int xcd = fid & 7, idx = fid >> 3;
    const int bh  = xcd * 16 + (idx >> 3);
    const int qt  = idx & 7;
    const int b = bh >> 4, h = bh & 15;
    const int wrow = qt*128 + w*32;
    const size_t rowbase = (size_t)b * S_;

    bf16x8 qa[2][2];
    #pragma unroll
    for (int g = 0; g < 2; g++) {
        const bf16* qp = Q + (rowbase + wrow + g*16 + l15)*DM + h*DEP + quad*8;
        qa[g][0] = *(const bf16x8*)qp;
        qa[g][1] = *(const bf16x8*)(qp + 32);
    }
    const bf16* kgbase = K + rowbase*DM + h*DEP;
    const bf16* vgbase = VtG + (size_t)(b*16 + h)*64*S_;
    const unsigned long long* mbase[2];
    #pragma unroll
    for (int g = 0; g < 2; g++)
        mbase[g] = mb + ((size_t)h*S_ + wrow + g*16 + l15) * 16;   // u64 per 64-k tile, q = l15

    // per-lane mask bit positions (iteration-invariant)
    uint32_t bmr[4];
    #pragma unroll
    for (int r = 0; r < 4; r++) bmr[r] = 1u << (quad*4 + r);

    bf16x4 onesv;
    #pragma unroll
    for (int r = 0; r < 4; r++) onesv[r] = (bf16)1.0f;

    f32x4 oT[2][4];           // O^T: [d = dt*16 + quad*4 + r][q = l15]
    f32x4 lacc[2];            // ones-row mfma accumulator: all entries == sum_k P[k][q]
    #pragma unroll
    for (int g = 0; g < 2; g++) {
        lacc[g] = f32x4{0.f,0.f,0.f,0.f};
        #pragma unroll
        for (int dt = 0; dt < 4; dt++) oT[g][dt] = f32x4{0.f,0.f,0.f,0.f};
    }

    // staging geometry: tile = 64 rows x 8 chunks of 16B (512 chunks). Per gld_lds
    // issue q, wave w covers LDS chunks [q*256+w*64, +64): lane l -> row q*32+w*8+(l>>3),
    // linear slot l&7. Swizzle: LDS slot s of row r holds GLOBAL chunk s^(r&7), so the
    // source chunk is pre-permuted: gch = (l&7) ^ (l>>3).
    const int srow8 = l >> 3;
    const int gch   = (l & 7) ^ srow8;

    // stage tile 0 into buffer 0
    #pragma unroll
    for (int q = 0; q < 2; q++) {
        const int row = q*32 + w*8 + srow8;
        gld_lds16(kgbase + (size_t)row*DM + gch*8, Ksm + (q*256 + w*64)*8);
        gld_lds16(vgbase + (size_t)row*S_ + gch*8, Vsm + (q*256 + w*64)*8);
    }

    const int rsw = l15 & 7;   // read-side swizzle key (row&7 for all read rows)

    for (int it = 0; it < 16; it++) {
        // Single barrier: implicit vmcnt(0) drains tile-`it` gld_lds writes AND
        // guarantees everyone finished reading buf[nxt] (read during it-1).
        __syncthreads();
        const int cur = (it & 1) * 4096, nxt = cur ^ 4096;
        const bf16* Kc = Ksm + cur;
        const bf16* Vc = Vsm + cur;

        // current-iter mask (first use is after kf reads + QK mfmas: latency covered)
        uint32_t cm[2][2];
        #pragma unroll
        for (int g = 0; g < 2; g++) {
            const unsigned long long mw = mbase[g][it];
            cm[g][0] = (uint32_t)mw; cm[g][1] = (uint32_t)(mw >> 32);
        }

        if (it + 1 < 16) {
            // prefetch tile it+1 straight into the other LDS buffer; drains at next barrier
            #pragma unroll
            for (int q = 0; q < 2; q++) {
                const int row = q*32 + w*8 + srow8;
                gld_lds16(kgbase + (size_t)((it+1)*64 + row)*DM + gch*8,
                          Ksm + nxt + (q*256 + w*64)*8);
                gld_lds16(vgbase + (size_t)row*S_ + (it+1)*64 + gch*8,
                          Vsm + nxt + (q*256 + w*64)*8);
            }
        }

        #pragma unroll
        for (int sub = 0; sub < 2; sub++) {
            bf16x8 kf[2][2];
            bf16x8 va8[4];
            #pragma unroll
            for (int h2 = 0; h2 < 2; h2++) {
                const int krow = sub*32 + h2*16 + l15;
                kf[h2][0] = *(const bf16x8*)(Kc + krow*64 + ((quad    ) ^ rsw)*8);
                kf[h2][1] = *(const bf16x8*)(Kc + krow*64 + ((quad + 4) ^ rsw)*8);
            }
            // k-permuted V: chunk (sub*4+quad) of row d holds [h2=0: r0..3 | h2=1: r0..3]
            #pragma unroll
            for (int dt = 0; dt < 4; dt++)
                va8[dt] = *(const bf16x8*)(Vc + (dt*16 + l15)*64 + ((sub*4 + quad) ^ rsw)*8);
            bf16x4 va[2][4];
            #pragma unroll
            for (int dt = 0; dt < 4; dt++)
                #pragma unroll
                for (int r = 0; r < 4; r++) {
                    va[0][dt][r] = va8[dt][r];
                    va[1][dt][r] = va8[dt][4 + r];
                }

            #pragma unroll
            for (int g = 0; g < 2; g++) {
                // S^T tiles: D[k_local = quad*4+r][q = l15]
                f32x4 st[2];
                __builtin_amdgcn_s_setprio(1);
                #pragma unroll
                for (int h2 = 0; h2 < 2; h2++) {
                    f32x4 z = {0.f,0.f,0.f,0.f};
                    z = __builtin_amdgcn_mfma_f32_16x16x32_bf16(kf[h2][0], qa[g][0], z, 0, 0, 0);
                    z = __builtin_amdgcn_mfma_f32_16x16x32_bf16(kf[h2][1], qa[g][1], z, 0, 0, 0);
                    st[h2] = z;
                }
                __builtin_amdgcn_s_setprio(0);
                const uint32_t msk = cm[g][sub];
                bf16x4 pb[2];
                #pragma unroll
                for (int h2 = 0; h2 < 2; h2++) {
                    const uint32_t mh = msk >> (h2 * 16);   // h2=0 is free
                    #pragma unroll
                    for (int r = 0; r < 4; r++) {
                        const float e = __builtin_amdgcn_exp2f(st[h2][r]);  // scale pre-folded into Q
                        const float pv = (mh & bmr[r]) ? e : 0.f;
                        pb[h2][r] = (bf16)pv;
                    }
                }
                __builtin_amdgcn_s_setprio(1);
                #pragma unroll
                for (int h2 = 0; h2 < 2; h2++) {
                    lacc[g] = mfma16(onesv, pb[h2], lacc[g]);   // denominator on the matrix pipe
                    #pragma unroll
                    for (int dt = 0; dt < 4; dt++)
                        oT[g][dt] = mfma16(va[h2][dt], pb[h2], oT[g][dt]);
                }
                __builtin_amdgcn_s_setprio(0);
            }
        }
    }

    #pragma unroll
    for (int g = 0; g < 2; g++) {
        const float inv = 1.0f / lacc[g][0];   // every lane holds the full column sum
        bf16* aor = AO + (rowbase + wrow + g*16 + l15)*DM + h*DEP;
        #pragma unroll
        for (int dt = 0; dt < 4; dt++) {
            bf16x4 ov;
            #pragma unroll
            for (int r = 0; r < 4; r++) ov[r] = (bf16)(oT[g][dt][r] * inv);
            *(bf16x4*)(aor + dt*16 + quad*4) = ov;
        }
    }
}

// ---------------------------------------------------------------- dense + residual (in-place R)
// v7: 64x128 tile -> grid (128,8) = 1024 blocks (was 512 at 128x128 = only 2
// blocks/CU = 2 waves/SIMD, half the latency hiding of every other kernel).
// Wave layout: 2x2, each wave 32 rows x 64 cols, acc[2][4]. LDS 12 KB.
__global__ __launch_bounds__(256) void dense_kernel(
    const bf16* __restrict__ AOin, const bf16* __restrict__ dT,
    const bf16* __restrict__ db, bf16* __restrict__ R)
{
    __shared__ alignas(16) bf16 Asm[64*32];
    __shared__ alignas(16) bf16 Bsm[128*32];
    const int m0 = blockIdx.x * 64, n0 = blockIdx.y * 128;
    const int tid = threadIdx.x, l = tid & 63, w = tid >> 6;
    const int wm = w >> 1, wn = w & 1, quad = l >> 4, l15 = l & 15;

    f32x4 acc[2][4];
    #pragma unroll
    for (int i = 0; i < 2; i++)
        #pragma unroll
        for (int j = 0; j < 4; j++) acc[i][j] = f32x4{0.f, 0.f, 0.f, 0.f};

    for (int k0 = 0; k0 < DM; k0 += 32) {
        __syncthreads();
        {   // A-tile: 64 rows x 4 chunks = 256 chunks, one per thread
            const int row = tid >> 2;
            gld_lds16(AOin + (size_t)(m0 + row)*DM + k0 + (tid & 3)*8, Asm + (w*64)*8);
        }
        #pragma unroll
        for (int qq = 0; qq < 2; qq++) {   // B-tile: 128 rows x 4 chunks
            const int c = qq*256 + tid;
            const int row = c >> 2, ch = c & 3;
            gld_lds16(dT + (size_t)(n0 + row)*DM + k0 + ch*8, Bsm + (qq*256 + w*64)*8);
        }
        __syncthreads();
        bf16x8 af[2], bfv[4];
        #pragma unroll
        for (int i = 0; i < 2; i++)
            af[i] = *(const bf16x8*)(Asm + (wm*32 + i*16 + l15)*32 + quad*8);
        #pragma unroll
        for (int j = 0; j < 4; j++)
            bfv[j] = *(const bf16x8*)(Bsm + (wn*64 + j*16 + l15)*32 + quad*8);
        #pragma unroll
        for (int i = 0; i < 2; i++)
            #pragma unroll
            for (int j = 0; j < 4; j++)
                acc[i][j] = __builtin_amdgcn_mfma_f32_16x16x32_bf16(af[i], bfv[j], acc[i][j], 0, 0, 0);
    }

    #pragma unroll
    for (int j = 0; j < 4; j++) {
        const int col = n0 + wn*64 + j*16 + l15;
        const float bv = (float)db[col];
        #pragma unroll
        for (int i = 0; i < 2; i++) {
            const int rb = m0 + wm*32 + i*16 + quad*4;
            #pragma unroll
            for (int r = 0; r < 4; r++) {
                const size_t idx = (size_t)(rb + r)*DM + col;
                R[idx] = (bf16)((float)R[idx] + acc[i][j][r] + bv);
            }
        }
    }
}

// ---------------------------------------------------------------- LayerNorm -> out (bf16 or f32)
__global__ __launch_bounds__(256) void ln_kernel(
    const bf16* __restrict__ R, const bf16* __restrict__ small,
    void* __restrict__ out, const int* __restrict__ flag)
{
    const int isb = *flag;
    __shared__ float red[8];
    const int row = blockIdx.x, tid = threadIdx.x;
    const bf16x4 rv = *(const bf16x4*)(R + (size_t)row*DM + tid*4);
    const float vx = (float)rv[0], vy = (float)rv[1], vz = (float)rv[2], vw = (float)rv[3];
    float s = vx + vy + vz + vw;
    #pragma unroll
    for (int m = 1; m < 64; m <<= 1) s += __shfl_xor(s, m);
    const int w = tid >> 6;
    if ((tid & 63) == 0) red[w] = s;
    __syncthreads();
    const float mu = (red[0] + red[1] + red[2] + red[3]) * (1.0f/DM);
    const float dx = vx - mu, dy = vy - mu, dz = vz - mu, dw = vw - mu;
    float q = dx*dx + dy*dy + dz*dz + dw*dw;
    #pragma unroll
    for (int m = 1; m < 64; m <<= 1) q += __shfl_xor(q, m);
    if ((tid & 63) == 0) red[4 + w] = q;
    __syncthreads();
    const float var = (red[4] + red[5] + red[6] + red[7]) * (1.0f/DM);
    const float rstd = rsqrtf(var + 1e-5f);
    const int col = tid * 4;
    const bf16x4 gv = *(const bf16x4*)(small + 4*1024 + col);
    const bf16x4 bv = *(const bf16x4*)(small + 5*1024 + col);
    const float o0 = dx*rstd*(float)gv[0] + (float)bv[0];
    const float o1 = dy*rstd*(float)gv[1] + (float)bv[1];
    const float o2 = dz*rstd*(float)gv[2] + (float)bv[2];
    const float o3 = dw*rstd*(float)gv[3] + (float)bv[3];
    if (isb) {
        bf16x4 ov; ov[0] = (bf16)o0; ov[1] = (bf16)o1; ov[2] = (bf16)o2; ov[3] = (bf16)o3;
        *(bf16x4*)((bf16*)out + (size_t)row*DM + col) = ov;
    } else {
        float4 ov = {o0, o1, o2, o3};
        *(float4*)((float*)out + (size_t)row*DM + col) = ov;
    }
}

// ---------------------------------------------------------------- launch
extern "C" void kernel_launch(void* const* d_in, const int* in_sizes, int n_in,
                              void* d_out, int out_size, void* d_ws, size_t ws_size,
                              hipStream_t stream) {
    const int* mask = (const int*)d_in[1];

    char* ws = (char*)d_ws;
    bf16* wqT   = (bf16*)(ws);
    bf16* wkT   = (bf16*)(ws + ((size_t)1 << 20));
    bf16* wvT   = (bf16*)(ws + ((size_t)2 << 20));
    bf16* resT  = (bf16*)(ws + ((size_t)3 << 20));
    bf16* dT    = (bf16*)(ws + ((size_t)4 << 20));   // 2 MB
    bf16* small = (bf16*)(ws + ((size_t)6 << 20));   // 12 KB
    int*  flag  = (int*) (ws + ((size_t)6 << 20) + 16384);
    unsigned long long* mbits = (unsigned long long*)(ws + ((size_t)7 << 20)); // 2 MB
    bf16* Qb    = (bf16*)(ws + ((size_t)9  << 20));  // 16 MB (also AO)
    bf16* Kb    = (bf16*)(ws + ((size_t)25 << 20));  // 16 MB
    bf16* VtG   = (bf16*)(ws + ((size_t)41 << 20));  // 16 MB, V transposed [bh][d][s-perm]
    bf16* R     = (bf16*)(ws + ((size_t)57 << 20));  // 16 MB; total 73 MB
    bf16* xc    = (bf16*)d_out;                      // dead until ln_kernel

    detect_kernel<<<1, 64, 0, stream>>>((const uint16_t*)d_in[0], flag);
    transpose_kernel<<<dim3(32, 16, 6), dim3(32, 8), 0, stream>>>(
        d_in[2], d_in[4], d_in[6], d_in[10], d_in[8],
        wqT, wkT, wvT, resT, dT, flag);
    xconv_kernel<<<4096, 256, 0, stream>>>(d_in[0], xc, flag);
    smallconv_kernel<<<6, 256, 0, stream>>>(
        d_in[3], d_in[5], d_in[7], d_in[9], d_in[11], d_in[12], small, flag);
    maskpack_kernel<<<1024, 256, 0, stream>>>(mask, mbits);
    proj_kernel<<<dim3(64, 32), 256, 0, stream>>>(
        xc, wqT, wkT, wvT, resT, small, Qb, Kb, VtG, R);
    attn_kernel<<<dim3(8, 128), 256, 0, stream>>>(Qb, Kb, VtG, mbits, Qb /*AO aliases Q*/);
    dense_kernel<<<dim3(128, 8), 256, 0, stream>>>(Qb, dT, small + 3*1024, R);
    ln_kernel<<<8192, 256, 0, stream>>>(R, small, d_out, flag);
}

// Round 4
// 384.777 us; speedup vs baseline: 1.0661x; 1.0661x over previous
//
#include <hip/hip_runtime.h>
#include <stdint.h>

#define B_ 8
#define S_ 1024
#define IN_DIM 512
#define DM 1024
#define H_ 16
#define DEP 64

typedef __bf16 bf16;
typedef __attribute__((ext_vector_type(8))) __bf16 bf16x8;
typedef __attribute__((ext_vector_type(4))) __bf16 bf16x4;
typedef __attribute__((ext_vector_type(4))) short short4v;
typedef __attribute__((ext_vector_type(4))) float f32x4;

// mfma 16x16x16 bf16: prefer gfx950-style name, fall back to CDNA2 _1k name.
#if defined(__has_builtin)
#if __has_builtin(__builtin_amdgcn_mfma_f32_16x16x16_bf16)
#define HAVE_NEW16 1
#endif
#endif
static __device__ __forceinline__ f32x4 mfma16(bf16x4 a, bf16x4 b, f32x4 c) {
#ifdef HAVE_NEW16
    return __builtin_amdgcn_mfma_f32_16x16x16_bf16(a, b, c, 0, 0, 0);
#else
    union { bf16x4 h; short4v s; } ua, ub;
    ua.h = a; ub.h = b;
    return __builtin_amdgcn_mfma_f32_16x16x16bf16_1k(ua.s, ub.s, c, 0, 0, 0);
#endif
}

// ---------------------------------------------------------------- async copy
static __device__ __forceinline__ void gld_lds16(const void* g, void* l) {
    __builtin_amdgcn_global_load_lds(
        (const __attribute__((address_space(1))) uint32_t*)g,
        (__attribute__((address_space(3))) uint32_t*)l, 16, 0, 0);
}

// ---------------------------------------------------------------- dtype detect
__global__ void detect_kernel(const uint16_t* __restrict__ xraw, int* __restrict__ flag) {
    const int t = threadIdx.x;  // 64 threads
    int sane = 0;
    #pragma unroll
    for (int j = 0; j < 8; j++) {
        const uint16_t u = xraw[t * 8 + j];
        const int e = (u >> 7) & 0xff;
        sane += ((u & 0x7fff) == 0 || (e >= 100 && e <= 140)) ? 1 : 0;
    }
    #pragma unroll
    for (int m = 1; m < 64; m <<= 1) sane += __shfl_xor(sane, m);
    if (t == 0) *flag = (sane >= 450) ? 1 : 0;
}

static __device__ __forceinline__ float ldin(const void* p, size_t i, int isb) {
    return isb ? (float)((const bf16*)p)[i] : ((const float*)p)[i];
}

// ---------------------------------------------------------------- weights -> bf16 [N][K]
__global__ __launch_bounds__(256) void transpose_kernel(
    const void* __restrict__ wq, const void* __restrict__ wk, const void* __restrict__ wv,
    const void* __restrict__ res, const void* __restrict__ dense,
    bf16* __restrict__ wqT, bf16* __restrict__ wkT, bf16* __restrict__ wvT,
    bf16* __restrict__ resT, bf16* __restrict__ denseT, const int* __restrict__ flag)
{
    const int isb = *flag;
    __shared__ bf16 tile[32][33];
    const int z = blockIdx.z;
    const void* src; bf16* dst; int kb, kd;
    if (z == 0)      { src = wq;    dst = wqT;    kb = 0;   kd = 512;  }
    else if (z == 1) { src = wk;    dst = wkT;    kb = 0;   kd = 512;  }
    else if (z == 2) { src = wv;    dst = wvT;    kb = 0;   kd = 512;  }
    else if (z == 3) { src = res;   dst = resT;   kb = 0;   kd = 512;  }
    else if (z == 4) { src = dense; dst = denseT; kb = 0;   kd = 1024; }
    else             { src = dense; dst = denseT; kb = 512; kd = 1024; }
    const int n0 = blockIdx.x * 32, k0 = blockIdx.y * 32;
    const int tx = threadIdx.x, ty = threadIdx.y;
    #pragma unroll
    for (int r = 0; r < 4; r++)
        tile[ty + r*8][tx] = (bf16)ldin(src, (size_t)(kb + k0 + ty + r*8) * DM + n0 + tx, isb);
    __syncthreads();
    #pragma unroll
    for (int r = 0; r < 4; r++)
        dst[(size_t)(n0 + ty + r*8) * kd + kb + k0 + tx] = tile[tx][ty + r*8];
}

// ---------------------------------------------------------------- x -> bf16
__global__ __launch_bounds__(256) void xconv_kernel(
    const void* __restrict__ x, bf16* __restrict__ xc, const int* __restrict__ flag)
{
    const int isb = *flag;
    const size_t i = ((size_t)blockIdx.x * 256 + threadIdx.x) * 4;
    #pragma unroll
    for (int j = 0; j < 4; j++) xc[i + j] = (bf16)ldin(x, i + j, isb);
}

// ---------------------------------------------------------------- small vectors -> bf16
// order: [wq_b, wk_b, wv_b, dense_b, ln_g, ln_b], each 1024
__global__ __launch_bounds__(256) void smallconv_kernel(
    const void* b0, const void* b1, const void* b2, const void* b3,
    const void* b4, const void* b5, bf16* __restrict__ out, const int* __restrict__ flag)
{
    const int isb = *flag;
    const void* srcs[6] = {b0, b1, b2, b3, b4, b5};
    const void* s = srcs[blockIdx.x];
    for (int i = threadIdx.x; i < 1024; i += 256)
        out[blockIdx.x * 1024 + i] = (bf16)ldin(s, i, isb);
}

// ---------------------------------------------------------------- mask -> bit pack (64 MB -> 2 MB)
__global__ __launch_bounds__(256) void maskpack_kernel(
    const int* __restrict__ mask, unsigned long long* __restrict__ mb)
{
    const int w = threadIdx.x >> 6, lane = threadIdx.x & 63;
    const int gw = blockIdx.x * 4 + w;           // 4096 waves
    for (int c = gw; c < 262144; c += 4096) {
        const int v = mask[(size_t)c * 64 + lane];
        const unsigned long long bits = __ballot(v != 0);
        if (lane == 0) mb[c] = bits;
    }
}

// ---------------------------------------------------------------- GEMM core 128x128 (async global->LDS, m97-style)
template<int KDIM>
static __device__ __forceinline__ void gemm_core(
    const bf16* __restrict__ A, const bf16* __restrict__ BT,
    int m0, int n0, bf16* Asm, bf16* Bsm, f32x4 acc[4][4])
{
    const int tid = threadIdx.x, l = tid & 63, w = tid >> 6;
    const int wm = w >> 1, wn = w & 1, quad = l >> 4, l15 = l & 15;
    #pragma unroll
    for (int i = 0; i < 4; i++)
        #pragma unroll
        for (int j = 0; j < 4; j++) acc[i][j] = f32x4{0.f, 0.f, 0.f, 0.f};

    for (int k0 = 0; k0 < KDIM; k0 += 32) {
        __syncthreads();
        #pragma unroll
        for (int qq = 0; qq < 2; qq++) {
            const int c = qq*256 + tid;
            const int row = c >> 2, ch = c & 3;      // [128 rows][4 chunks of 8 bf16]
            gld_lds16(A  + (size_t)(m0 + row)*KDIM + k0 + ch*8, Asm + (qq*256 + w*64)*8);
            gld_lds16(BT + (size_t)(n0 + row)*KDIM + k0 + ch*8, Bsm + (qq*256 + w*64)*8);
        }
        __syncthreads();
        bf16x8 af[4], bfv[4];
        #pragma unroll
        for (int i = 0; i < 4; i++)
            af[i] = *(const bf16x8*)(Asm + (wm*64 + i*16 + l15)*32 + quad*8);
        #pragma unroll
        for (int j = 0; j < 4; j++)
            bfv[j] = *(const bf16x8*)(Bsm + (wn*64 + j*16 + l15)*32 + quad*8);
        #pragma unroll
        for (int i = 0; i < 4; i++)
            #pragma unroll
            for (int j = 0; j < 4; j++)
                acc[i][j] = __builtin_amdgcn_mfma_f32_16x16x32_bf16(af[i], bfv[j], acc[i][j], 0, 0, 0);
    }
}

// ---------------------------------------------------------------- QKV + residual projection
// grid (64, 32). sel: 0=Q (scaled 0.125*log2(e) so attn can use raw v_exp_f32),
// 1=K, 2=V (written transposed [bh][d][s], k-PERMUTED within 32-blocks), 3=residual.
#define EPI_P 132
__global__ __launch_bounds__(256) void proj_kernel(
    const bf16* __restrict__ x,
    const bf16* __restrict__ wqT, const bf16* __restrict__ wkT,
    const bf16* __restrict__ wvT, const bf16* __restrict__ resT,
    const bf16* __restrict__ small,
    bf16* __restrict__ Q, bf16* __restrict__ K, bf16* __restrict__ VtG, bf16* __restrict__ R)
{
    __shared__ alignas(16) char smem[17408];   // union: staging (16384) | V-epilogue (16896)
    bf16* Asm = (bf16*)smem;
    bf16* Bsm = (bf16*)(smem + 8192);
    bf16* epi = (bf16*)smem;                   // [64 cols][EPI_P] rows-pitch

    const int m0 = blockIdx.x * 128;
    const int ng = blockIdx.y * 128;
    const int sel = ng >> 10, n0 = ng & 1023;
    const bf16* BT; const bf16* bias = nullptr;
    if (sel == 0)      { BT = wqT; bias = small;        }
    else if (sel == 1) { BT = wkT; bias = small + 1024; }
    else if (sel == 2) { BT = wvT; bias = small + 2048; }
    else               { BT = resT; }

    f32x4 acc[4][4];
    gemm_core<IN_DIM>(x, BT, m0, n0, Asm, Bsm, acc);

    const int tid = threadIdx.x, l = tid & 63, w = tid >> 6;
    const int wm = w >> 1, wn = w & 1, quad = l >> 4, l15 = l & 15;

    if (sel == 2) {
        // V: stage [col][row] in LDS, emit transposed VtG[(b*16+h)*64 + d][s'] coalesced.
        // s' is k-PERMUTED within each 32-block: position p holds source
        // kl = ((p&4)<<2) | ((p&24)>>1) | (p&3)   (i.e. p = quad*8 + h2*4 + r for
        // kl = h2*16 + quad*4 + r). This lets attn fetch both h2 fragments of a
        // (sub,quad) pair with ONE ds_read_b128, conflict-free under 8-lane phasing.
        const int bb = m0 >> 10, srow0 = m0 & 1023;
        #pragma unroll
        for (int hf = 0; hf < 2; hf++) {
            __syncthreads();
            if (wn == hf) {
                #pragma unroll
                for (int j = 0; j < 4; j++) {
                    const int cl = j*16 + l15;
                    const float bv = (float)bias[n0 + hf*64 + cl];
                    #pragma unroll
                    for (int i = 0; i < 4; i++) {
                        const int rho = wm*64 + i*16 + quad*4;
                        #pragma unroll
                        for (int r = 0; r < 4; r++)
                            epi[cl*EPI_P + rho + r] = (bf16)(acc[i][j][r] + bv);
                    }
                }
            }
            __syncthreads();
            const int hh = (n0 >> 6) + hf;
            const int sc = tid & 15;
            #pragma unroll
            for (int pass = 0; pass < 4; pass++) {
                const int dl = (tid >> 4) + pass*16;
                bf16x8 v;
                #pragma unroll
                for (int k = 0; k < 8; k++) {
                    const int pl = (sc & 3)*8 + k;                                  // pos in 32-block
                    const int kl = ((pl & 4) << 2) | ((pl & 24) >> 1) | (pl & 3);   // source pos
                    v[k] = epi[dl*EPI_P + (sc >> 2)*32 + kl];
                }
                *(bf16x8*)(VtG + ((size_t)(bb*16 + hh)*64 + dl)*S_ + srow0 + sc*8) = v;
            }
        }
        return;
    }

    #pragma unroll
    for (int j = 0; j < 4; j++) {
        const int col = n0 + wn*64 + j*16 + l15;
        const float bv = (sel < 3) ? (float)bias[col] : 0.f;
        #pragma unroll
        for (int i = 0; i < 4; i++) {
            const int rb = m0 + wm*64 + i*16 + quad*4;
            #pragma unroll
            for (int r = 0; r < 4; r++) {
                const float v = acc[i][j][r] + bv;
                // 0.125 * log2(e) = 0.18033688011112042: scores land in base-2 domain,
                // attn_kernel then uses raw v_exp_f32 (2^x) with no per-element multiply.
                if (sel == 0)      Q[(size_t)(rb + r)*DM + col] = (bf16)(v * 0.18033688f);
                else if (sel == 1) K[(size_t)(rb + r)*DM + col] = (bf16)v;
                else               R[(size_t)(rb + r)*DM + col] = (bf16)v;
            }
        }
    }
}

// ---------------------------------------------------------------- flash attention v8
// vs v7: the v7 regression (FETCH 69->370MB, WRITE 33->171MB) was SCRATCH traffic
// from the element-wise unpack  va[h2][dt][r] = va8[dt][r or 4+r]  (compiler demoted
// the element-constructed vector array to scratch; rule #20 family). v8 removes the
// construction entirely: bf16x8 occupies 4 VGPRs, its bf16x4 halves are register
// pairs, so __builtin_shufflevector(va8,va8,0..3/4..7) is a zero-cost subregister
// alias fed straight to mfma16. Bank-conflict fix of v7 (k-permuted V + one b128
// read per (sub,dt)) is retained - it verified (4.19M -> 0).
// grid (8, 128): block = 128 q-rows of one (b,h); wave = 32 q-rows (2 groups of 16).
__global__ __launch_bounds__(256, 4) void attn_kernel(
    const bf16* __restrict__ Q, const bf16* __restrict__ K, const bf16* __restrict__ VtG,
    const unsigned long long* __restrict__ mb, bf16* __restrict__ AO)
{
    __shared__ alignas(16) bf16 Ksm[2*64*64];   // dbuf [krow][d], 16B-chunk XOR-swizzled
    __shared__ alignas(16) bf16 Vsm[2*64*64];   // dbuf [d][k-permuted], same swizzle

    const int tid = threadIdx.x, l = tid & 63, w = tid >> 6;
    const int quad = l >> 4, l15 = l & 15;

    // XCD swizzle: flat id f lands on XCD f%8 (round-robin dispatch). Remap so each
    // XCD owns 16 complete (b,h) groups incl. all 8 q-tiles (1024 % 8 == 0, bijective).
    const int fid = blockIdx.y * 8 + blockIdx.x;
    const int xcd = fid & 7, idx = fid >> 3;
    const int bh  = xcd * 16 + (idx >> 3);
    const int qt  = idx & 7;
    const int b = bh >> 4, h = bh & 15;
    const int wrow = qt*128 + w*32;
    const size_t rowbase = (size_t)b * S_;

    bf16x8 qa[2][2];
    #pragma unroll
    for (int g = 0; g < 2; g++) {
        const bf16* qp = Q + (rowbase + wrow + g*16 + l15)*DM + h*DEP + quad*8;
        qa[g][0] = *(const bf16x8*)qp;
        qa[g][1] = *(const bf16x8*)(qp + 32);
    }
    const bf16* kgbase = K + rowbase*DM + h*DEP;
    const bf16* vgbase = VtG + (size_t)(b*16 + h)*64*S_;
    const unsigned long long* mbase[2];
    #pragma unroll
    for (int g = 0; g < 2; g++)
        mbase[g] = mb + ((size_t)h*S_ + wrow + g*16 + l15) * 16;   // u64 per 64-k tile, q = l15

    // per-lane mask bit positions (iteration-invariant)
    uint32_t bmr[4];
    #pragma unroll
    for (int r = 0; r < 4; r++) bmr[r] = 1u << (quad*4 + r);

    bf16x4 onesv;
    #pragma unroll
    for (int r = 0; r < 4; r++) onesv[r] = (bf16)1.0f;

    f32x4 oT[2][4];           // O^T: [d = dt*16 + quad*4 + r][q = l15]
    f32x4 lacc[2];            // ones-row mfma accumulator: all entries == sum_k P[k][q]
    #pragma unroll
    for (int g = 0; g < 2; g++) {
        lacc[g] = f32x4{0.f,0.f,0.f,0.f};
        #pragma unroll
        for (int dt = 0; dt < 4; dt++) oT[g][dt] = f32x4{0.f,0.f,0.f,0.f};
    }

    // staging geometry: tile = 64 rows x 8 chunks of 16B (512 chunks). Per gld_lds
    // issue q, wave w covers LDS chunks [q*256+w*64, +64): lane l -> row q*32+w*8+(l>>3),
    // linear slot l&7. Swizzle: LDS slot s of row r holds GLOBAL chunk s^(r&7), so the
    // source chunk is pre-permuted: gch = (l&7) ^ (l>>3).
    const int srow8 = l >> 3;
    const int gch   = (l & 7) ^ srow8;

    // stage tile 0 into buffer 0
    #pragma unroll
    for (int q = 0; q < 2; q++) {
        const int row = q*32 + w*8 + srow8;
        gld_lds16(kgbase + (size_t)row*DM + gch*8, Ksm + (q*256 + w*64)*8);
        gld_lds16(vgbase + (size_t)row*S_ + gch*8, Vsm + (q*256 + w*64)*8);
    }

    const int rsw = l15 & 7;   // read-side swizzle key (row&7 for all read rows)

    for (int it = 0; it < 16; it++) {
        // Single barrier: implicit vmcnt(0) drains tile-`it` gld_lds writes AND
        // guarantees everyone finished reading buf[nxt] (read during it-1).
        __syncthreads();
        const int cur = (it & 1) * 4096, nxt = cur ^ 4096;
        const bf16* Kc = Ksm + cur;
        const bf16* Vc = Vsm + cur;

        // current-iter mask (first use is after kf reads + QK mfmas: latency covered)
        uint32_t cm[2][2];
        #pragma unroll
        for (int g = 0; g < 2; g++) {
            const unsigned long long mw = mbase[g][it];
            cm[g][0] = (uint32_t)mw; cm[g][1] = (uint32_t)(mw >> 32);
        }

        if (it + 1 < 16) {
            // prefetch tile it+1 straight into the other LDS buffer; drains at next barrier
            #pragma unroll
            for (int q = 0; q < 2; q++) {
                const int row = q*32 + w*8 + srow8;
                gld_lds16(kgbase + (size_t)((it+1)*64 + row)*DM + gch*8,
                          Ksm + nxt + (q*256 + w*64)*8);
                gld_lds16(vgbase + (size_t)row*S_ + (it+1)*64 + gch*8,
                          Vsm + nxt + (q*256 + w*64)*8);
            }
        }

        #pragma unroll
        for (int sub = 0; sub < 2; sub++) {
            bf16x8 kf[2][2];
            bf16x8 va8[4];
            #pragma unroll
            for (int h2 = 0; h2 < 2; h2++) {
                const int krow = sub*32 + h2*16 + l15;
                kf[h2][0] = *(const bf16x8*)(Kc + krow*64 + ((quad    ) ^ rsw)*8);
                kf[h2][1] = *(const bf16x8*)(Kc + krow*64 + ((quad + 4) ^ rsw)*8);
            }
            // k-permuted V: chunk (sub*4+quad) of row d holds [h2=0: r0..3 | h2=1: r0..3]
            #pragma unroll
            for (int dt = 0; dt < 4; dt++)
                va8[dt] = *(const bf16x8*)(Vc + (dt*16 + l15)*64 + ((sub*4 + quad) ^ rsw)*8);

            #pragma unroll
            for (int g = 0; g < 2; g++) {
                // S^T tiles: D[k_local = quad*4+r][q = l15]
                f32x4 st[2];
                __builtin_amdgcn_s_setprio(1);
                #pragma unroll
                for (int h2 = 0; h2 < 2; h2++) {
                    f32x4 z = {0.f,0.f,0.f,0.f};
                    z = __builtin_amdgcn_mfma_f32_16x16x32_bf16(kf[h2][0], qa[g][0], z, 0, 0, 0);
                    z = __builtin_amdgcn_mfma_f32_16x16x32_bf16(kf[h2][1], qa[g][1], z, 0, 0, 0);
                    st[h2] = z;
                }
                __builtin_amdgcn_s_setprio(0);
                const uint32_t msk = cm[g][sub];
                bf16x4 pb[2];
                #pragma unroll
                for (int h2 = 0; h2 < 2; h2++) {
                    const uint32_t mh = msk >> (h2 * 16);   // h2=0 is free
                    #pragma unroll
                    for (int r = 0; r < 4; r++) {
                        const float e = __builtin_amdgcn_exp2f(st[h2][r]);  // scale pre-folded into Q
                        const float pv = (mh & bmr[r]) ? e : 0.f;
                        pb[h2][r] = (bf16)pv;
                    }
                }
                __builtin_amdgcn_s_setprio(1);
                #pragma unroll
                for (int h2 = 0; h2 < 2; h2++) {
                    lacc[g] = mfma16(onesv, pb[h2], lacc[g]);   // denominator on the matrix pipe
                    #pragma unroll
                    for (int dt = 0; dt < 4; dt++) {
                        // zero-cost subregister halves of va8 (NO element-wise array build:
                        // that was v7's scratch explosion)
                        const bf16x4 vh = h2
                            ? __builtin_shufflevector(va8[dt], va8[dt], 4, 5, 6, 7)
                            : __builtin_shufflevector(va8[dt], va8[dt], 0, 1, 2, 3);
                        oT[g][dt] = mfma16(vh, pb[h2], oT[g][dt]);
                    }
                }
                __builtin_amdgcn_s_setprio(0);
            }
        }
    }

    #pragma unroll
    for (int g = 0; g < 2; g++) {
        const float inv = 1.0f / lacc[g][0];   // every lane holds the full column sum
        bf16* aor = AO + (rowbase + wrow + g*16 + l15)*DM + h*DEP;
        #pragma unroll
        for (int dt = 0; dt < 4; dt++) {
            bf16x4 ov;
            #pragma unroll
            for (int r = 0; r < 4; r++) ov[r] = (bf16)(oT[g][dt][r] * inv);
            *(bf16x4*)(aor + dt*16 + quad*4) = ov;
        }
    }
}

// ---------------------------------------------------------------- dense + residual (in-place R)
// 64x128 tile -> grid (128,8) = 1024 blocks (vs 512 at 128x128 = only 2 blocks/CU).
// Wave layout: 2x2, each wave 32 rows x 64 cols, acc[2][4]. LDS 12 KB.
__global__ __launch_bounds__(256) void dense_kernel(
    const bf16* __restrict__ AOin, const bf16* __restrict__ dT,
    const bf16* __restrict__ db, bf16* __restrict__ R)
{
    __shared__ alignas(16) bf16 Asm[64*32];
    __shared__ alignas(16) bf16 Bsm[128*32];
    const int m0 = blockIdx.x * 64, n0 = blockIdx.y * 128;
    const int tid = threadIdx.x, l = tid & 63, w = tid >> 6;
    const int wm = w >> 1, wn = w & 1, quad = l >> 4, l15 = l & 15;

    f32x4 acc[2][4];
    #pragma unroll
    for (int i = 0; i < 2; i++)
        #pragma unroll
        for (int j = 0; j < 4; j++) acc[i][j] = f32x4{0.f, 0.f, 0.f, 0.f};

    for (int k0 = 0; k0 < DM; k0 += 32) {
        __syncthreads();
        {   // A-tile: 64 rows x 4 chunks = 256 chunks, one per thread
            const int row = tid >> 2;
            gld_lds16(AOin + (size_t)(m0 + row)*DM + k0 + (tid & 3)*8, Asm + (w*64)*8);
        }
        #pragma unroll
        for (int qq = 0; qq < 2; qq++) {   // B-tile: 128 rows x 4 chunks
            const int c = qq*256 + tid;
            const int row = c >> 2, ch = c & 3;
            gld_lds16(dT + (size_t)(n0 + row)*DM + k0 + ch*8, Bsm + (qq*256 + w*64)*8);
        }
        __syncthreads();
        bf16x8 af[2], bfv[4];
        #pragma unroll
        for (int i = 0; i < 2; i++)
            af[i] = *(const bf16x8*)(Asm + (wm*32 + i*16 + l15)*32 + quad*8);
        #pragma unroll
        for (int j = 0; j < 4; j++)
            bfv[j] = *(const bf16x8*)(Bsm + (wn*64 + j*16 + l15)*32 + quad*8);
        #pragma unroll
        for (int i = 0; i < 2; i++)
            #pragma unroll
            for (int j = 0; j < 4; j++)
                acc[i][j] = __builtin_amdgcn_mfma_f32_16x16x32_bf16(af[i], bfv[j], acc[i][j], 0, 0, 0);
    }

    #pragma unroll
    for (int j = 0; j < 4; j++) {
        const int col = n0 + wn*64 + j*16 + l15;
        const float bv = (float)db[col];
        #pragma unroll
        for (int i = 0; i < 2; i++) {
            const int rb = m0 + wm*32 + i*16 + quad*4;
            #pragma unroll
            for (int r = 0; r < 4; r++) {
                const size_t idx = (size_t)(rb + r)*DM + col;
                R[idx] = (bf16)((float)R[idx] + acc[i][j][r] + bv);
            }
        }
    }
}

// ---------------------------------------------------------------- LayerNorm -> out (bf16 or f32)
__global__ __launch_bounds__(256) void ln_kernel(
    const bf16* __restrict__ R, const bf16* __restrict__ small,
    void* __restrict__ out, const int* __restrict__ flag)
{
    const int isb = *flag;
    __shared__ float red[8];
    const int row = blockIdx.x, tid = threadIdx.x;
    const bf16x4 rv = *(const bf16x4*)(R + (size_t)row*DM + tid*4);
    const float vx = (float)rv[0], vy = (float)rv[1], vz = (float)rv[2], vw = (float)rv[3];
    float s = vx + vy + vz + vw;
    #pragma unroll
    for (int m = 1; m < 64; m <<= 1) s += __shfl_xor(s, m);
    const int w = tid >> 6;
    if ((tid & 63) == 0) red[w] = s;
    __syncthreads();
    const float mu = (red[0] + red[1] + red[2] + red[3]) * (1.0f/DM);
    const float dx = vx - mu, dy = vy - mu, dz = vz - mu, dw = vw - mu;
    float q = dx*dx + dy*dy + dz*dz + dw*dw;
    #pragma unroll
    for (int m = 1; m < 64; m <<= 1) q += __shfl_xor(q, m);
    if ((tid & 63) == 0) red[4 + w] = q;
    __syncthreads();
    const float var = (red[4] + red[5] + red[6] + red[7]) * (1.0f/DM);
    const float rstd = rsqrtf(var + 1e-5f);
    const int col = tid * 4;
    const bf16x4 gv = *(const bf16x4*)(small + 4*1024 + col);
    const bf16x4 bv = *(const bf16x4*)(small + 5*1024 + col);
    const float o0 = dx*rstd*(float)gv[0] + (float)bv[0];
    const float o1 = dy*rstd*(float)gv[1] + (float)bv[1];
    const float o2 = dz*rstd*(float)gv[2] + (float)bv[2];
    const float o3 = dw*rstd*(float)gv[3] + (float)bv[3];
    if (isb) {
        bf16x4 ov; ov[0] = (bf16)o0; ov[1] = (bf16)o1; ov[2] = (bf16)o2; ov[3] = (bf16)o3;
        *(bf16x4*)((bf16*)out + (size_t)row*DM + col) = ov;
    } else {
        float4 ov = {o0, o1, o2, o3};
        *(float4*)((float*)out + (size_t)row*DM + col) = ov;
    }
}

// ---------------------------------------------------------------- launch
extern "C" void kernel_launch(void* const* d_in, const int* in_sizes, int n_in,
                              void* d_out, int out_size, void* d_ws, size_t ws_size,
                              hipStream_t stream) {
    const int* mask = (const int*)d_in[1];

    char* ws = (char*)d_ws;
    bf16* wqT   = (bf16*)(ws);
    bf16* wkT   = (bf16*)(ws + ((size_t)1 << 20));
    bf16* wvT   = (bf16*)(ws + ((size_t)2 << 20));
    bf16* resT  = (bf16*)(ws + ((size_t)3 << 20));
    bf16* dT    = (bf16*)(ws + ((size_t)4 << 20));   // 2 MB
    bf16* small = (bf16*)(ws + ((size_t)6 << 20));   // 12 KB
    int*  flag  = (int*) (ws + ((size_t)6 << 20) + 16384);
    unsigned long long* mbits = (unsigned long long*)(ws + ((size_t)7 << 20)); // 2 MB
    bf16* Qb    = (bf16*)(ws + ((size_t)9  << 20));  // 16 MB (also AO)
    bf16* Kb    = (bf16*)(ws + ((size_t)25 << 20));  // 16 MB
    bf16* VtG   = (bf16*)(ws + ((size_t)41 << 20));  // 16 MB, V transposed [bh][d][s-perm]
    bf16* R     = (bf16*)(ws + ((size_t)57 << 20));  // 16 MB; total 73 MB
    bf16* xc    = (bf16*)d_out;                      // dead until ln_kernel

    detect_kernel<<<1, 64, 0, stream>>>((const uint16_t*)d_in[0], flag);
    transpose_kernel<<<dim3(32, 16, 6), dim3(32, 8), 0, stream>>>(
        d_in[2], d_in[4], d_in[6], d_in[10], d_in[8],
        wqT, wkT, wvT, resT, dT, flag);
    xconv_kernel<<<4096, 256, 0, stream>>>(d_in[0], xc, flag);
    smallconv_kernel<<<6, 256, 0, stream>>>(
        d_in[3], d_in[5], d_in[7], d_in[9], d_in[11], d_in[12], small, flag);
    maskpack_kernel<<<1024, 256, 0, stream>>>(mask, mbits);
    proj_kernel<<<dim3(64, 32), 256, 0, stream>>>(
        xc, wqT, wkT, wvT, resT, small, Qb, Kb, VtG, R);
    attn_kernel<<<dim3(8, 128), 256, 0, stream>>>(Qb, Kb, VtG, mbits, Qb /*AO aliases Q*/);
    dense_kernel<<<dim3(128, 8), 256, 0, stream>>>(Qb, dT, small + 3*1024, R);
    ln_kernel<<<8192, 256, 0, stream>>>(R, small, d_out, flag);
}

// Round 6
// 351.061 us; speedup vs baseline: 1.1685x; 1.0960x over previous
//
#include <hip/hip_runtime.h>
#include <stdint.h>

#define B_ 8
#define S_ 1024
#define IN_DIM 512
#define DM 1024
#define H_ 16
#define DEP 64

typedef __bf16 bf16;
typedef __attribute__((ext_vector_type(8))) __bf16 bf16x8;
typedef __attribute__((ext_vector_type(4))) __bf16 bf16x4;
typedef __attribute__((ext_vector_type(4))) short short4v;
typedef __attribute__((ext_vector_type(4))) float f32x4;

// mfma 16x16x16 bf16: prefer gfx950-style name, fall back to CDNA2 _1k name.
#if defined(__has_builtin)
#if __has_builtin(__builtin_amdgcn_mfma_f32_16x16x16_bf16)
#define HAVE_NEW16 1
#endif
#endif
static __device__ __forceinline__ f32x4 mfma16(bf16x4 a, bf16x4 b, f32x4 c) {
#ifdef HAVE_NEW16
    return __builtin_amdgcn_mfma_f32_16x16x16_bf16(a, b, c, 0, 0, 0);
#else
    union { bf16x4 h; short4v s; } ua, ub;
    ua.h = a; ub.h = b;
    return __builtin_amdgcn_mfma_f32_16x16x16bf16_1k(ua.s, ub.s, c, 0, 0, 0);
#endif
}

// ---------------------------------------------------------------- async copy
static __device__ __forceinline__ void gld_lds16(const void* g, void* l) {
    __builtin_amdgcn_global_load_lds(
        (const __attribute__((address_space(1))) uint32_t*)g,
        (__attribute__((address_space(3))) uint32_t*)l, 16, 0, 0);
}

// ---------------------------------------------------------------- dtype detect
__global__ void detect_kernel(const uint16_t* __restrict__ xraw, int* __restrict__ flag) {
    const int t = threadIdx.x;  // 64 threads
    int sane = 0;
    #pragma unroll
    for (int j = 0; j < 8; j++) {
        const uint16_t u = xraw[t * 8 + j];
        const int e = (u >> 7) & 0xff;
        sane += ((u & 0x7fff) == 0 || (e >= 100 && e <= 140)) ? 1 : 0;
    }
    #pragma unroll
    for (int m = 1; m < 64; m <<= 1) sane += __shfl_xor(sane, m);
    if (t == 0) *flag = (sane >= 450) ? 1 : 0;
}

static __device__ __forceinline__ float ldin(const void* p, size_t i, int isb) {
    return isb ? (float)((const bf16*)p)[i] : ((const float*)p)[i];
}

// ---------------------------------------------------------------- weights -> bf16 [N][K]
__global__ __launch_bounds__(256) void transpose_kernel(
    const void* __restrict__ wq, const void* __restrict__ wk, const void* __restrict__ wv,
    const void* __restrict__ res, const void* __restrict__ dense,
    bf16* __restrict__ wqT, bf16* __restrict__ wkT, bf16* __restrict__ wvT,
    bf16* __restrict__ resT, bf16* __restrict__ denseT, const int* __restrict__ flag)
{
    const int isb = *flag;
    __shared__ bf16 tile[32][33];
    const int z = blockIdx.z;
    const void* src; bf16* dst; int kb, kd;
    if (z == 0)      { src = wq;    dst = wqT;    kb = 0;   kd = 512;  }
    else if (z == 1) { src = wk;    dst = wkT;    kb = 0;   kd = 512;  }
    else if (z == 2) { src = wv;    dst = wvT;    kb = 0;   kd = 512;  }
    else if (z == 3) { src = res;   dst = resT;   kb = 0;   kd = 512;  }
    else if (z == 4) { src = dense; dst = denseT; kb = 0;   kd = 1024; }
    else             { src = dense; dst = denseT; kb = 512; kd = 1024; }
    const int n0 = blockIdx.x * 32, k0 = blockIdx.y * 32;
    const int tx = threadIdx.x, ty = threadIdx.y;
    #pragma unroll
    for (int r = 0; r < 4; r++)
        tile[ty + r*8][tx] = (bf16)ldin(src, (size_t)(kb + k0 + ty + r*8) * DM + n0 + tx, isb);
    __syncthreads();
    #pragma unroll
    for (int r = 0; r < 4; r++)
        dst[(size_t)(n0 + ty + r*8) * kd + kb + k0 + tx] = tile[tx][ty + r*8];
}

// ---------------------------------------------------------------- x -> bf16
__global__ __launch_bounds__(256) void xconv_kernel(
    const void* __restrict__ x, bf16* __restrict__ xc, const int* __restrict__ flag)
{
    const int isb = *flag;
    const size_t i = ((size_t)blockIdx.x * 256 + threadIdx.x) * 4;
    #pragma unroll
    for (int j = 0; j < 4; j++) xc[i + j] = (bf16)ldin(x, i + j, isb);
}

// ---------------------------------------------------------------- small vectors -> bf16
// order: [wq_b, wk_b, wv_b, dense_b, ln_g, ln_b], each 1024
__global__ __launch_bounds__(256) void smallconv_kernel(
    const void* b0, const void* b1, const void* b2, const void* b3,
    const void* b4, const void* b5, bf16* __restrict__ out, const int* __restrict__ flag)
{
    const int isb = *flag;
    const void* srcs[6] = {b0, b1, b2, b3, b4, b5};
    const void* s = srcs[blockIdx.x];
    for (int i = threadIdx.x; i < 1024; i += 256)
        out[blockIdx.x * 1024 + i] = (bf16)ldin(s, i, isb);
}

// ---------------------------------------------------------------- mask -> bit pack (64 MB -> 2 MB)
__global__ __launch_bounds__(256) void maskpack_kernel(
    const int* __restrict__ mask, unsigned long long* __restrict__ mb)
{
    const int w = threadIdx.x >> 6, lane = threadIdx.x & 63;
    const int gw = blockIdx.x * 4 + w;           // 4096 waves
    for (int c = gw; c < 262144; c += 4096) {
        const int v = mask[(size_t)c * 64 + lane];
        const unsigned long long bits = __ballot(v != 0);
        if (lane == 0) mb[c] = bits;
    }
}

// ---------------------------------------------------------------- GEMM core 128x128 (async global->LDS, m97-style)
template<int KDIM>
static __device__ __forceinline__ void gemm_core(
    const bf16* __restrict__ A, const bf16* __restrict__ BT,
    int m0, int n0, bf16* Asm, bf16* Bsm, f32x4 acc[4][4])
{
    const int tid = threadIdx.x, l = tid & 63, w = tid >> 6;
    const int wm = w >> 1, wn = w & 1, quad = l >> 4, l15 = l & 15;
    #pragma unroll
    for (int i = 0; i < 4; i++)
        #pragma unroll
        for (int j = 0; j < 4; j++) acc[i][j] = f32x4{0.f, 0.f, 0.f, 0.f};

    for (int k0 = 0; k0 < KDIM; k0 += 32) {
        __syncthreads();
        #pragma unroll
        for (int qq = 0; qq < 2; qq++) {
            const int c = qq*256 + tid;
            const int row = c >> 2, ch = c & 3;      // [128 rows][4 chunks of 8 bf16]
            gld_lds16(A  + (size_t)(m0 + row)*KDIM + k0 + ch*8, Asm + (qq*256 + w*64)*8);
            gld_lds16(BT + (size_t)(n0 + row)*KDIM + k0 + ch*8, Bsm + (qq*256 + w*64)*8);
        }
        __syncthreads();
        bf16x8 af[4], bfv[4];
        #pragma unroll
        for (int i = 0; i < 4; i++)
            af[i] = *(const bf16x8*)(Asm + (wm*64 + i*16 + l15)*32 + quad*8);
        #pragma unroll
        for (int j = 0; j < 4; j++)
            bfv[j] = *(const bf16x8*)(Bsm + (wn*64 + j*16 + l15)*32 + quad*8);
        #pragma unroll
        for (int i = 0; i < 4; i++)
            #pragma unroll
            for (int j = 0; j < 4; j++)
                acc[i][j] = __builtin_amdgcn_mfma_f32_16x16x32_bf16(af[i], bfv[j], acc[i][j], 0, 0, 0);
    }
}

// ---------------------------------------------------------------- QKV + residual projection
// grid (64, 32). sel: 0=Q (scaled 0.125*log2(e) so attn can use raw v_exp_f32),
// 1=K, 2=V (written transposed [bh][d][s], k-PERMUTED within 32-blocks), 3=residual.
#define EPI_P 132
__global__ __launch_bounds__(256) void proj_kernel(
    const bf16* __restrict__ x,
    const bf16* __restrict__ wqT, const bf16* __restrict__ wkT,
    const bf16* __restrict__ wvT, const bf16* __restrict__ resT,
    const bf16* __restrict__ small,
    bf16* __restrict__ Q, bf16* __restrict__ K, bf16* __restrict__ VtG, bf16* __restrict__ R)
{
    __shared__ alignas(16) char smem[17408];   // union: staging (16384) | V-epilogue (16896)
    bf16* Asm = (bf16*)smem;
    bf16* Bsm = (bf16*)(smem + 8192);
    bf16* epi = (bf16*)smem;                   // [64 cols][EPI_P] rows-pitch

    const int m0 = blockIdx.x * 128;
    const int ng = blockIdx.y * 128;
    const int sel = ng >> 10, n0 = ng & 1023;
    const bf16* BT; const bf16* bias = nullptr;
    if (sel == 0)      { BT = wqT; bias = small;        }
    else if (sel == 1) { BT = wkT; bias = small + 1024; }
    else if (sel == 2) { BT = wvT; bias = small + 2048; }
    else               { BT = resT; }

    f32x4 acc[4][4];
    gemm_core<IN_DIM>(x, BT, m0, n0, Asm, Bsm, acc);

    const int tid = threadIdx.x, l = tid & 63, w = tid >> 6;
    const int wm = w >> 1, wn = w & 1, quad = l >> 4, l15 = l & 15;

    if (sel == 2) {
        // V: stage [col][row] in LDS, emit transposed VtG[(b*16+h)*64 + d][s'] coalesced.
        // s' is k-PERMUTED within each 32-block: position p holds source
        // kl = ((p&4)<<2) | ((p&24)>>1) | (p&3)   (i.e. p = quad*8 + h2*4 + r for
        // kl = h2*16 + quad*4 + r). This lets attn fetch both h2 fragments of a
        // (sub,quad) pair with ONE ds_read_b128, conflict-free under 8-lane phasing.
        const int bb = m0 >> 10, srow0 = m0 & 1023;
        #pragma unroll
        for (int hf = 0; hf < 2; hf++) {
            __syncthreads();
            if (wn == hf) {
                #pragma unroll
                for (int j = 0; j < 4; j++) {
                    const int cl = j*16 + l15;
                    const float bv = (float)bias[n0 + hf*64 + cl];
                    #pragma unroll
                    for (int i = 0; i < 4; i++) {
                        const int rho = wm*64 + i*16 + quad*4;
                        #pragma unroll
                        for (int r = 0; r < 4; r++)
                            epi[cl*EPI_P + rho + r] = (bf16)(acc[i][j][r] + bv);
                    }
                }
            }
            __syncthreads();
            const int hh = (n0 >> 6) + hf;
            const int sc = tid & 15;
            #pragma unroll
            for (int pass = 0; pass < 4; pass++) {
                const int dl = (tid >> 4) + pass*16;
                bf16x8 v;
                #pragma unroll
                for (int k = 0; k < 8; k++) {
                    const int pl = (sc & 3)*8 + k;                                  // pos in 32-block
                    const int kl = ((pl & 4) << 2) | ((pl & 24) >> 1) | (pl & 3);   // source pos
                    v[k] = epi[dl*EPI_P + (sc >> 2)*32 + kl];
                }
                *(bf16x8*)(VtG + ((size_t)(bb*16 + hh)*64 + dl)*S_ + srow0 + sc*8) = v;
            }
        }
        return;
    }

    #pragma unroll
    for (int j = 0; j < 4; j++) {
        const int col = n0 + wn*64 + j*16 + l15;
        const float bv = (sel < 3) ? (float)bias[col] : 0.f;
        #pragma unroll
        for (int i = 0; i < 4; i++) {
            const int rb = m0 + wm*64 + i*16 + quad*4;
            #pragma unroll
            for (int r = 0; r < 4; r++) {
                const float v = acc[i][j][r] + bv;
                // 0.125 * log2(e) = 0.18033688011112042: scores land in base-2 domain,
                // attn_kernel then uses raw v_exp_f32 (2^x) with no per-element multiply.
                if (sel == 0)      Q[(size_t)(rb + r)*DM + col] = (bf16)(v * 0.18033688f);
                else if (sel == 1) K[(size_t)(rb + r)*DM + col] = (bf16)v;
                else               R[(size_t)(rb + r)*DM + col] = (bf16)v;
            }
        }
    }
}

// ---------------------------------------------------------------- flash attention v9
// vs v8: ONE change - drop the ",4" min-waves bound. Session VGPR/WRITE trace:
//   r0 lb(256):   VGPR 112, WRITE 16.4MB (= AO exactly, zero scratch)
//   r1-r4 lb(256,4): VGPR pinned 64, scratch WRITE 21->171->115MB as reg demand grew.
// The forced 64-VGPR allocation spills everything past 64 to scratch; occupancy
// bought by the bound only hides scratch-induced latency. Let the allocator take
// ~110-130 VGPRs; zero scratch at ~2-3 blocks/CU is the better trade (r0 proved
// this structure runs fine at 19.6% occupancy).
// grid (8, 128): block = 128 q-rows of one (b,h); wave = 32 q-rows (2 groups of 16).
__global__ __launch_bounds__(256) void attn_kernel(
    const bf16* __restrict__ Q, const bf16* __restrict__ K, const bf16* __restrict__ VtG,
    const unsigned long long* __restrict__ mb, bf16* __restrict__ AO)
{
    __shared__ alignas(16) bf16 Ksm[2*64*64];   // dbuf [krow][d], 16B-chunk XOR-swizzled
    __shared__ alignas(16) bf16 Vsm[2*64*64];   // dbuf [d][k-permuted], same swizzle

    const int tid = threadIdx.x, l = tid & 63, w = tid >> 6;
    const int quad = l >> 4, l15 = l & 15;

    // XCD swizzle: flat id f lands on XCD f%8 (round-robin dispatch). Remap so each
    // XCD owns 16 complete (b,h) groups incl. all 8 q-tiles (1024 % 8 == 0, bijective).
    const int fid = blockIdx.y * 8 + blockIdx.x;
    const int xcd = fid & 7, idx = fid >> 3;
    const int bh  = xcd * 16 + (idx >> 3);
    const int qt  = idx & 7;
    const int b = bh >> 4, h = bh & 15;
    const int wrow = qt*128 + w*32;
    const size_t rowbase = (size_t)b * S_;

    bf16x8 qa[2][2];
    #pragma unroll
    for (int g = 0; g < 2; g++) {
        const bf16* qp = Q + (rowbase + wrow + g*16 + l15)*DM + h*DEP + quad*8;
        qa[g][0] = *(const bf16x8*)qp;
        qa[g][1] = *(const bf16x8*)(qp + 32);
    }
    const bf16* kgbase = K + rowbase*DM + h*DEP;
    const bf16* vgbase = VtG + (size_t)(b*16 + h)*64*S_;
    const unsigned long long* mbase[2];
    #pragma unroll
    for (int g = 0; g < 2; g++)
        mbase[g] = mb + ((size_t)h*S_ + wrow + g*16 + l15) * 16;   // u64 per 64-k tile, q = l15

    // per-lane mask bit positions (iteration-invariant)
    uint32_t bmr[4];
    #pragma unroll
    for (int r = 0; r < 4; r++) bmr[r] = 1u << (quad*4 + r);

    bf16x4 onesv;
    #pragma unroll
    for (int r = 0; r < 4; r++) onesv[r] = (bf16)1.0f;

    f32x4 oT[2][4];           // O^T: [d = dt*16 + quad*4 + r][q = l15]
    f32x4 lacc[2];            // ones-row mfma accumulator: all entries == sum_k P[k][q]
    #pragma unroll
    for (int g = 0; g < 2; g++) {
        lacc[g] = f32x4{0.f,0.f,0.f,0.f};
        #pragma unroll
        for (int dt = 0; dt < 4; dt++) oT[g][dt] = f32x4{0.f,0.f,0.f,0.f};
    }

    // staging geometry: tile = 64 rows x 8 chunks of 16B (512 chunks). Per gld_lds
    // issue q, wave w covers LDS chunks [q*256+w*64, +64): lane l -> row q*32+w*8+(l>>3),
    // linear slot l&7. Swizzle: LDS slot s of row r holds GLOBAL chunk s^(r&7), so the
    // source chunk is pre-permuted: gch = (l&7) ^ (l>>3).
    const int srow8 = l >> 3;
    const int gch   = (l & 7) ^ srow8;

    // stage tile 0 into buffer 0
    #pragma unroll
    for (int q = 0; q < 2; q++) {
        const int row = q*32 + w*8 + srow8;
        gld_lds16(kgbase + (size_t)row*DM + gch*8, Ksm + (q*256 + w*64)*8);
        gld_lds16(vgbase + (size_t)row*S_ + gch*8, Vsm + (q*256 + w*64)*8);
    }

    const int rsw = l15 & 7;   // read-side swizzle key (row&7 for all read rows)

    for (int it = 0; it < 16; it++) {
        // Single barrier: implicit vmcnt(0) drains tile-`it` gld_lds writes AND
        // guarantees everyone finished reading buf[nxt] (read during it-1).
        __syncthreads();
        const int cur = (it & 1) * 4096, nxt = cur ^ 4096;
        const bf16* Kc = Ksm + cur;
        const bf16* Vc = Vsm + cur;

        // current-iter mask (first use is after kf reads + QK mfmas: latency covered)
        uint32_t cm[2][2];
        #pragma unroll
        for (int g = 0; g < 2; g++) {
            const unsigned long long mw = mbase[g][it];
            cm[g][0] = (uint32_t)mw; cm[g][1] = (uint32_t)(mw >> 32);
        }

        if (it + 1 < 16) {
            // prefetch tile it+1 straight into the other LDS buffer; drains at next barrier
            #pragma unroll
            for (int q = 0; q < 2; q++) {
                const int row = q*32 + w*8 + srow8;
                gld_lds16(kgbase + (size_t)((it+1)*64 + row)*DM + gch*8,
                          Ksm + nxt + (q*256 + w*64)*8);
                gld_lds16(vgbase + (size_t)row*S_ + (it+1)*64 + gch*8,
                          Vsm + nxt + (q*256 + w*64)*8);
            }
        }

        #pragma unroll
        for (int sub = 0; sub < 2; sub++) {
            bf16x8 kf[2][2];
            bf16x8 va8[4];
            #pragma unroll
            for (int h2 = 0; h2 < 2; h2++) {
                const int krow = sub*32 + h2*16 + l15;
                kf[h2][0] = *(const bf16x8*)(Kc + krow*64 + ((quad    ) ^ rsw)*8);
                kf[h2][1] = *(const bf16x8*)(Kc + krow*64 + ((quad + 4) ^ rsw)*8);
            }
            // k-permuted V: chunk (sub*4+quad) of row d holds [h2=0: r0..3 | h2=1: r0..3]
            #pragma unroll
            for (int dt = 0; dt < 4; dt++)
                va8[dt] = *(const bf16x8*)(Vc + (dt*16 + l15)*64 + ((sub*4 + quad) ^ rsw)*8);

            #pragma unroll
            for (int g = 0; g < 2; g++) {
                // S^T tiles: D[k_local = quad*4+r][q = l15]
                f32x4 st[2];
                __builtin_amdgcn_s_setprio(1);
                #pragma unroll
                for (int h2 = 0; h2 < 2; h2++) {
                    f32x4 z = {0.f,0.f,0.f,0.f};
                    z = __builtin_amdgcn_mfma_f32_16x16x32_bf16(kf[h2][0], qa[g][0], z, 0, 0, 0);
                    z = __builtin_amdgcn_mfma_f32_16x16x32_bf16(kf[h2][1], qa[g][1], z, 0, 0, 0);
                    st[h2] = z;
                }
                __builtin_amdgcn_s_setprio(0);
                const uint32_t msk = cm[g][sub];
                bf16x4 pb[2];
                #pragma unroll
                for (int h2 = 0; h2 < 2; h2++) {
                    const uint32_t mh = msk >> (h2 * 16);   // h2=0 is free
                    #pragma unroll
                    for (int r = 0; r < 4; r++) {
                        const float e = __builtin_amdgcn_exp2f(st[h2][r]);  // scale pre-folded into Q
                        const float pv = (mh & bmr[r]) ? e : 0.f;
                        pb[h2][r] = (bf16)pv;
                    }
                }
                __builtin_amdgcn_s_setprio(1);
                #pragma unroll
                for (int h2 = 0; h2 < 2; h2++) {
                    lacc[g] = mfma16(onesv, pb[h2], lacc[g]);   // denominator on the matrix pipe
                    #pragma unroll
                    for (int dt = 0; dt < 4; dt++) {
                        // zero-cost subregister halves of va8 (NO element-wise array build)
                        const bf16x4 vh = h2
                            ? __builtin_shufflevector(va8[dt], va8[dt], 4, 5, 6, 7)
                            : __builtin_shufflevector(va8[dt], va8[dt], 0, 1, 2, 3);
                        oT[g][dt] = mfma16(vh, pb[h2], oT[g][dt]);
                    }
                }
                __builtin_amdgcn_s_setprio(0);
            }
        }
    }

    #pragma unroll
    for (int g = 0; g < 2; g++) {
        const float inv = 1.0f / lacc[g][0];   // every lane holds the full column sum
        bf16* aor = AO + (rowbase + wrow + g*16 + l15)*DM + h*DEP;
        #pragma unroll
        for (int dt = 0; dt < 4; dt++) {
            bf16x4 ov;
            #pragma unroll
            for (int r = 0; r < 4; r++) ov[r] = (bf16)(oT[g][dt][r] * inv);
            *(bf16x4*)(aor + dt*16 + quad*4) = ov;
        }
    }
}

// ---------------------------------------------------------------- dense + residual (in-place R)
// 64x128 tile -> grid (128,8) = 1024 blocks (vs 512 at 128x128 = only 2 blocks/CU).
// Wave layout: 2x2, each wave 32 rows x 64 cols, acc[2][4]. LDS 12 KB.
__global__ __launch_bounds__(256) void dense_kernel(
    const bf16* __restrict__ AOin, const bf16* __restrict__ dT,
    const bf16* __restrict__ db, bf16* __restrict__ R)
{
    __shared__ alignas(16) bf16 Asm[64*32];
    __shared__ alignas(16) bf16 Bsm[128*32];
    const int m0 = blockIdx.x * 64, n0 = blockIdx.y * 128;
    const int tid = threadIdx.x, l = tid & 63, w = tid >> 6;
    const int wm = w >> 1, wn = w & 1, quad = l >> 4, l15 = l & 15;

    f32x4 acc[2][4];
    #pragma unroll
    for (int i = 0; i < 2; i++)
        #pragma unroll
        for (int j = 0; j < 4; j++) acc[i][j] = f32x4{0.f, 0.f, 0.f, 0.f};

    for (int k0 = 0; k0 < DM; k0 += 32) {
        __syncthreads();
        {   // A-tile: 64 rows x 4 chunks = 256 chunks, one per thread
            const int row = tid >> 2;
            gld_lds16(AOin + (size_t)(m0 + row)*DM + k0 + (tid & 3)*8, Asm + (w*64)*8);
        }
        #pragma unroll
        for (int qq = 0; qq < 2; qq++) {   // B-tile: 128 rows x 4 chunks
            const int c = qq*256 + tid;
            const int row = c >> 2, ch = c & 3;
            gld_lds16(dT + (size_t)(n0 + row)*DM + k0 + ch*8, Bsm + (qq*256 + w*64)*8);
        }
        __syncthreads();
        bf16x8 af[2], bfv[4];
        #pragma unroll
        for (int i = 0; i < 2; i++)
            af[i] = *(const bf16x8*)(Asm + (wm*32 + i*16 + l15)*32 + quad*8);
        #pragma unroll
        for (int j = 0; j < 4; j++)
            bfv[j] = *(const bf16x8*)(Bsm + (wn*64 + j*16 + l15)*32 + quad*8);
        #pragma unroll
        for (int i = 0; i < 2; i++)
            #pragma unroll
            for (int j = 0; j < 4; j++)
                acc[i][j] = __builtin_amdgcn_mfma_f32_16x16x32_bf16(af[i], bfv[j], acc[i][j], 0, 0, 0);
    }

    #pragma unroll
    for (int j = 0; j < 4; j++) {
        const int col = n0 + wn*64 + j*16 + l15;
        const float bv = (float)db[col];
        #pragma unroll
        for (int i = 0; i < 2; i++) {
            const int rb = m0 + wm*32 + i*16 + quad*4;
            #pragma unroll
            for (int r = 0; r < 4; r++) {
                const size_t idx = (size_t)(rb + r)*DM + col;
                R[idx] = (bf16)((float)R[idx] + acc[i][j][r] + bv);
            }
        }
    }
}

// ---------------------------------------------------------------- LayerNorm -> out (bf16 or f32)
__global__ __launch_bounds__(256) void ln_kernel(
    const bf16* __restrict__ R, const bf16* __restrict__ small,
    void* __restrict__ out, const int* __restrict__ flag)
{
    const int isb = *flag;
    __shared__ float red[8];
    const int row = blockIdx.x, tid = threadIdx.x;
    const bf16x4 rv = *(const bf16x4*)(R + (size_t)row*DM + tid*4);
    const float vx = (float)rv[0], vy = (float)rv[1], vz = (float)rv[2], vw = (float)rv[3];
    float s = vx + vy + vz + vw;
    #pragma unroll
    for (int m = 1; m < 64; m <<= 1) s += __shfl_xor(s, m);
    const int w = tid >> 6;
    if ((tid & 63) == 0) red[w] = s;
    __syncthreads();
    const float mu = (red[0] + red[1] + red[2] + red[3]) * (1.0f/DM);
    const float dx = vx - mu, dy = vy - mu, dz = vz - mu, dw = vw - mu;
    float q = dx*dx + dy*dy + dz*dz + dw*dw;
    #pragma unroll
    for (int m = 1; m < 64; m <<= 1) q += __shfl_xor(q, m);
    if ((tid & 63) == 0) red[4 + w] = q;
    __syncthreads();
    const float var = (red[4] + red[5] + red[6] + red[7]) * (1.0f/DM);
    const float rstd = rsqrtf(var + 1e-5f);
    const int col = tid * 4;
    const bf16x4 gv = *(const bf16x4*)(small + 4*1024 + col);
    const bf16x4 bv = *(const bf16x4*)(small + 5*1024 + col);
    const float o0 = dx*rstd*(float)gv[0] + (float)bv[0];
    const float o1 = dy*rstd*(float)gv[1] + (float)bv[1];
    const float o2 = dz*rstd*(float)gv[2] + (float)bv[2];
    const float o3 = dw*rstd*(float)gv[3] + (float)bv[3];
    if (isb) {
        bf16x4 ov; ov[0] = (bf16)o0; ov[1] = (bf16)o1; ov[2] = (bf16)o2; ov[3] = (bf16)o3;
        *(bf16x4*)((bf16*)out + (size_t)row*DM + col) = ov;
    } else {
        float4 ov = {o0, o1, o2, o3};
        *(float4*)((float*)out + (size_t)row*DM + col) = ov;
    }
}

// ---------------------------------------------------------------- launch
extern "C" void kernel_launch(void* const* d_in, const int* in_sizes, int n_in,
                              void* d_out, int out_size, void* d_ws, size_t ws_size,
                              hipStream_t stream) {
    const int* mask = (const int*)d_in[1];

    char* ws = (char*)d_ws;
    bf16* wqT   = (bf16*)(ws);
    bf16* wkT   = (bf16*)(ws + ((size_t)1 << 20));
    bf16* wvT   = (bf16*)(ws + ((size_t)2 << 20));
    bf16* resT  = (bf16*)(ws + ((size_t)3 << 20));
    bf16* dT    = (bf16*)(ws + ((size_t)4 << 20));   // 2 MB
    bf16* small = (bf16*)(ws + ((size_t)6 << 20));   // 12 KB
    int*  flag  = (int*) (ws + ((size_t)6 << 20) + 16384);
    unsigned long long* mbits = (unsigned long long*)(ws + ((size_t)7 << 20)); // 2 MB
    bf16* Qb    = (bf16*)(ws + ((size_t)9  << 20));  // 16 MB (also AO)
    bf16* Kb    = (bf16*)(ws + ((size_t)25 << 20));  // 16 MB
    bf16* VtG   = (bf16*)(ws + ((size_t)41 << 20));  // 16 MB, V transposed [bh][d][s-perm]
    bf16* R     = (bf16*)(ws + ((size_t)57 << 20));  // 16 MB; total 73 MB
    bf16* xc    = (bf16*)d_out;                      // dead until ln_kernel

    detect_kernel<<<1, 64, 0, stream>>>((const uint16_t*)d_in[0], flag);
    transpose_kernel<<<dim3(32, 16, 6), dim3(32, 8), 0, stream>>>(
        d_in[2], d_in[4], d_in[6], d_in[10], d_in[8],
        wqT, wkT, wvT, resT, dT, flag);
    xconv_kernel<<<4096, 256, 0, stream>>>(d_in[0], xc, flag);
    smallconv_kernel<<<6, 256, 0, stream>>>(
        d_in[3], d_in[5], d_in[7], d_in[9], d_in[11], d_in[12], small, flag);
    maskpack_kernel<<<1024, 256, 0, stream>>>(mask, mbits);
    proj_kernel<<<dim3(64, 32), 256, 0, stream>>>(
        xc, wqT, wkT, wvT, resT, small, Qb, Kb, VtG, R);
    attn_kernel<<<dim3(8, 128), 256, 0, stream>>>(Qb, Kb, VtG, mbits, Qb /*AO aliases Q*/);
    dense_kernel<<<dim3(128, 8), 256, 0, stream>>>(Qb, dT, small + 3*1024, R);
    ln_kernel<<<8192, 256, 0, stream>>>(R, small, d_out, flag);
}

// Round 7
// 342.641 us; speedup vs baseline: 1.1972x; 1.0246x over previous
//
#include <hip/hip_runtime.h>
#include <stdint.h>

#define B_ 8
#define S_ 1024
#define IN_DIM 512
#define DM 1024
#define H_ 16
#define DEP 64

typedef __bf16 bf16;
typedef __attribute__((ext_vector_type(8))) __bf16 bf16x8;
typedef __attribute__((ext_vector_type(4))) __bf16 bf16x4;
typedef __attribute__((ext_vector_type(4))) short short4v;
typedef __attribute__((ext_vector_type(4))) float f32x4;

// mfma 16x16x16 bf16: prefer gfx950-style name, fall back to CDNA2 _1k name.
#if defined(__has_builtin)
#if __has_builtin(__builtin_amdgcn_mfma_f32_16x16x16_bf16)
#define HAVE_NEW16 1
#endif
#endif
static __device__ __forceinline__ f32x4 mfma16(bf16x4 a, bf16x4 b, f32x4 c) {
#ifdef HAVE_NEW16
    return __builtin_amdgcn_mfma_f32_16x16x16_bf16(a, b, c, 0, 0, 0);
#else
    union { bf16x4 h; short4v s; } ua, ub;
    ua.h = a; ub.h = b;
    return __builtin_amdgcn_mfma_f32_16x16x16bf16_1k(ua.s, ub.s, c, 0, 0, 0);
#endif
}

// ---------------------------------------------------------------- async copy
static __device__ __forceinline__ void gld_lds16(const void* g, void* l) {
    __builtin_amdgcn_global_load_lds(
        (const __attribute__((address_space(1))) uint32_t*)g,
        (__attribute__((address_space(3))) uint32_t*)l, 16, 0, 0);
}

// ---------------------------------------------------------------- dtype detect
__global__ void detect_kernel(const uint16_t* __restrict__ xraw, int* __restrict__ flag) {
    const int t = threadIdx.x;  // 64 threads
    int sane = 0;
    #pragma unroll
    for (int j = 0; j < 8; j++) {
        const uint16_t u = xraw[t * 8 + j];
        const int e = (u >> 7) & 0xff;
        sane += ((u & 0x7fff) == 0 || (e >= 100 && e <= 140)) ? 1 : 0;
    }
    #pragma unroll
    for (int m = 1; m < 64; m <<= 1) sane += __shfl_xor(sane, m);
    if (t == 0) *flag = (sane >= 450) ? 1 : 0;
}

static __device__ __forceinline__ float ldin(const void* p, size_t i, int isb) {
    return isb ? (float)((const bf16*)p)[i] : ((const float*)p)[i];
}

// ---------------------------------------------------------------- weights -> bf16 [N][K]
__global__ __launch_bounds__(256) void transpose_kernel(
    const void* __restrict__ wq, const void* __restrict__ wk, const void* __restrict__ wv,
    const void* __restrict__ res, const void* __restrict__ dense,
    bf16* __restrict__ wqT, bf16* __restrict__ wkT, bf16* __restrict__ wvT,
    bf16* __restrict__ resT, bf16* __restrict__ denseT, const int* __restrict__ flag)
{
    const int isb = *flag;
    __shared__ bf16 tile[32][33];
    const int z = blockIdx.z;
    const void* src; bf16* dst; int kb, kd;
    if (z == 0)      { src = wq;    dst = wqT;    kb = 0;   kd = 512;  }
    else if (z == 1) { src = wk;    dst = wkT;    kb = 0;   kd = 512;  }
    else if (z == 2) { src = wv;    dst = wvT;    kb = 0;   kd = 512;  }
    else if (z == 3) { src = res;   dst = resT;   kb = 0;   kd = 512;  }
    else if (z == 4) { src = dense; dst = denseT; kb = 0;   kd = 1024; }
    else             { src = dense; dst = denseT; kb = 512; kd = 1024; }
    const int n0 = blockIdx.x * 32, k0 = blockIdx.y * 32;
    const int tx = threadIdx.x, ty = threadIdx.y;
    #pragma unroll
    for (int r = 0; r < 4; r++)
        tile[ty + r*8][tx] = (bf16)ldin(src, (size_t)(kb + k0 + ty + r*8) * DM + n0 + tx, isb);
    __syncthreads();
    #pragma unroll
    for (int r = 0; r < 4; r++)
        dst[(size_t)(n0 + ty + r*8) * kd + kb + k0 + tx] = tile[tx][ty + r*8];
}

// ---------------------------------------------------------------- x -> bf16 (vectorized: float4 in, bf16x4 out)
__global__ __launch_bounds__(256) void xconv_kernel(
    const void* __restrict__ x, bf16* __restrict__ xc, const int* __restrict__ flag)
{
    const int isb = *flag;
    const size_t i = ((size_t)blockIdx.x * 256 + threadIdx.x) * 4;
    if (isb) {
        *(bf16x4*)(xc + i) = *(const bf16x4*)((const bf16*)x + i);
    } else {
        const float4 v = *(const float4*)((const float*)x + i);
        bf16x4 o; o[0] = (bf16)v.x; o[1] = (bf16)v.y; o[2] = (bf16)v.z; o[3] = (bf16)v.w;
        *(bf16x4*)(xc + i) = o;
    }
}

// ---------------------------------------------------------------- small vectors -> bf16
// order: [wq_b, wk_b, wv_b, dense_b, ln_g, ln_b], each 1024
__global__ __launch_bounds__(256) void smallconv_kernel(
    const void* b0, const void* b1, const void* b2, const void* b3,
    const void* b4, const void* b5, bf16* __restrict__ out, const int* __restrict__ flag)
{
    const int isb = *flag;
    const void* srcs[6] = {b0, b1, b2, b3, b4, b5};
    const void* s = srcs[blockIdx.x];
    for (int i = threadIdx.x; i < 1024; i += 256)
        out[blockIdx.x * 1024 + i] = (bf16)ldin(s, i, isb);
}

// ---------------------------------------------------------------- mask -> bit pack (64 MB -> 2 MB)
__global__ __launch_bounds__(256) void maskpack_kernel(
    const int* __restrict__ mask, unsigned long long* __restrict__ mb)
{
    const int w = threadIdx.x >> 6, lane = threadIdx.x & 63;
    const int gw = blockIdx.x * 4 + w;           // 4096 waves
    for (int c = gw; c < 262144; c += 4096) {
        const int v = mask[(size_t)c * 64 + lane];
        const unsigned long long bits = __ballot(v != 0);
        if (lane == 0) mb[c] = bits;
    }
}

// ---------------------------------------------------------------- GEMM core 128x128, DOUBLE-BUFFERED
// v10: attn-v9's proven single-barrier dbuf schedule ported to the GEMM staging.
// Old shape exposed full L2 latency EVERY k-iter (loads issued between two barriers,
// drained immediately by the 2nd). New shape: one barrier/iter; tile k+1's
// global_load_lds fly during tile k's ds_read+MFMA; the top-of-iter barrier's
// implicit vmcnt(0) drain publishes them. Asm/Bsm are 2x 128x32 halves (16 KB each).
template<int KDIM>
static __device__ __forceinline__ void gemm_core(
    const bf16* __restrict__ A, const bf16* __restrict__ BT,
    int m0, int n0, bf16* Asm, bf16* Bsm, f32x4 acc[4][4])
{
    const int tid = threadIdx.x, l = tid & 63, w = tid >> 6;
    const int wm = w >> 1, wn = w & 1, quad = l >> 4, l15 = l & 15;
    #pragma unroll
    for (int i = 0; i < 4; i++)
        #pragma unroll
        for (int j = 0; j < 4; j++) acc[i][j] = f32x4{0.f, 0.f, 0.f, 0.f};

    constexpr int NIT = KDIM / 32;
    const int srow = tid >> 2, sch = tid & 3;    // 128 rows x 4 chunks; also qq+1 row offset +64

    // prologue: stage tile 0 into half 0
    #pragma unroll
    for (int qq = 0; qq < 2; qq++) {
        const int row = qq*64 + srow;
        gld_lds16(A  + (size_t)(m0 + row)*KDIM + sch*8, Asm + (qq*256 + w*64)*8);
        gld_lds16(BT + (size_t)(n0 + row)*KDIM + sch*8, Bsm + (qq*256 + w*64)*8);
    }

    for (int it = 0; it < NIT; it++) {
        __syncthreads();   // drains stage(it) gld_lds; protects half (it^1) from overwrite-vs-read
        const int cur = (it & 1) * 4096;         // elements (8 KB halves)
        const int nxt = cur ^ 4096;
        if (it + 1 < NIT) {
            const int k1 = (it + 1) * 32;
            #pragma unroll
            for (int qq = 0; qq < 2; qq++) {
                const int row = qq*64 + srow;
                gld_lds16(A  + (size_t)(m0 + row)*KDIM + k1 + sch*8, Asm + nxt + (qq*256 + w*64)*8);
                gld_lds16(BT + (size_t)(n0 + row)*KDIM + k1 + sch*8, Bsm + nxt + (qq*256 + w*64)*8);
            }
        }
        bf16x8 af[4], bfv[4];
        #pragma unroll
        for (int i = 0; i < 4; i++)
            af[i] = *(const bf16x8*)(Asm + cur + (wm*64 + i*16 + l15)*32 + quad*8);
        #pragma unroll
        for (int j = 0; j < 4; j++)
            bfv[j] = *(const bf16x8*)(Bsm + cur + (wn*64 + j*16 + l15)*32 + quad*8);
        #pragma unroll
        for (int i = 0; i < 4; i++)
            #pragma unroll
            for (int j = 0; j < 4; j++)
                acc[i][j] = __builtin_amdgcn_mfma_f32_16x16x32_bf16(af[i], bfv[j], acc[i][j], 0, 0, 0);
    }
}

// ---------------------------------------------------------------- QKV + residual projection
// grid (64, 32). sel: 0=Q (scaled 0.125*log2(e) so attn can use raw v_exp_f32),
// 1=K, 2=V (written transposed [bh][d][s], k-PERMUTED within 32-blocks), 3=residual.
#define EPI_P 132
__global__ __launch_bounds__(256) void proj_kernel(
    const bf16* __restrict__ x,
    const bf16* __restrict__ wqT, const bf16* __restrict__ wkT,
    const bf16* __restrict__ wvT, const bf16* __restrict__ resT,
    const bf16* __restrict__ small,
    bf16* __restrict__ Q, bf16* __restrict__ K, bf16* __restrict__ VtG, bf16* __restrict__ R)
{
    __shared__ alignas(16) char smem[32768];   // dbuf staging (2x8KB A + 2x8KB B) | V-epilogue (16896) aliases
    bf16* Asm = (bf16*)smem;
    bf16* Bsm = (bf16*)(smem + 16384);
    bf16* epi = (bf16*)smem;                   // [64 cols][EPI_P] rows-pitch

    const int m0 = blockIdx.x * 128;
    const int ng = blockIdx.y * 128;
    const int sel = ng >> 10, n0 = ng & 1023;
    const bf16* BT; const bf16* bias = nullptr;
    if (sel == 0)      { BT = wqT; bias = small;        }
    else if (sel == 1) { BT = wkT; bias = small + 1024; }
    else if (sel == 2) { BT = wvT; bias = small + 2048; }
    else               { BT = resT; }

    f32x4 acc[4][4];
    gemm_core<IN_DIM>(x, BT, m0, n0, Asm, Bsm, acc);

    const int tid = threadIdx.x, l = tid & 63, w = tid >> 6;
    const int wm = w >> 1, wn = w & 1, quad = l >> 4, l15 = l & 15;

    if (sel == 2) {
        // V: stage [col][row] in LDS, emit transposed VtG[(b*16+h)*64 + d][s'] coalesced.
        // s' is k-PERMUTED within each 32-block: position p holds source
        // kl = ((p&4)<<2) | ((p&24)>>1) | (p&3)   (i.e. p = quad*8 + h2*4 + r for
        // kl = h2*16 + quad*4 + r). This lets attn fetch both h2 fragments of a
        // (sub,quad) pair with ONE ds_read_b128, conflict-free under 8-lane phasing.
        const int bb = m0 >> 10, srow0 = m0 & 1023;
        #pragma unroll
        for (int hf = 0; hf < 2; hf++) {
            __syncthreads();
            if (wn == hf) {
                #pragma unroll
                for (int j = 0; j < 4; j++) {
                    const int cl = j*16 + l15;
                    const float bv = (float)bias[n0 + hf*64 + cl];
                    #pragma unroll
                    for (int i = 0; i < 4; i++) {
                        const int rho = wm*64 + i*16 + quad*4;
                        #pragma unroll
                        for (int r = 0; r < 4; r++)
                            epi[cl*EPI_P + rho + r] = (bf16)(acc[i][j][r] + bv);
                    }
                }
            }
            __syncthreads();
            const int hh = (n0 >> 6) + hf;
            const int sc = tid & 15;
            #pragma unroll
            for (int pass = 0; pass < 4; pass++) {
                const int dl = (tid >> 4) + pass*16;
                bf16x8 v;
                #pragma unroll
                for (int k = 0; k < 8; k++) {
                    const int pl = (sc & 3)*8 + k;                                  // pos in 32-block
                    const int kl = ((pl & 4) << 2) | ((pl & 24) >> 1) | (pl & 3);   // source pos
                    v[k] = epi[dl*EPI_P + (sc >> 2)*32 + kl];
                }
                *(bf16x8*)(VtG + ((size_t)(bb*16 + hh)*64 + dl)*S_ + srow0 + sc*8) = v;
            }
        }
        return;
    }

    #pragma unroll
    for (int j = 0; j < 4; j++) {
        const int col = n0 + wn*64 + j*16 + l15;
        const float bv = (sel < 3) ? (float)bias[col] : 0.f;
        #pragma unroll
        for (int i = 0; i < 4; i++) {
            const int rb = m0 + wm*64 + i*16 + quad*4;
            #pragma unroll
            for (int r = 0; r < 4; r++) {
                const float v = acc[i][j][r] + bv;
                // 0.125 * log2(e) = 0.18033688011112042: scores land in base-2 domain,
                // attn_kernel then uses raw v_exp_f32 (2^x) with no per-element multiply.
                if (sel == 0)      Q[(size_t)(rb + r)*DM + col] = (bf16)(v * 0.18033688f);
                else if (sel == 1) K[(size_t)(rb + r)*DM + col] = (bf16)v;
                else               R[(size_t)(rb + r)*DM + col] = (bf16)v;
            }
        }
    }
}

// ---------------------------------------------------------------- flash attention v9 (unchanged, verified)
// r6 verified: VGPR 88, WRITE = AO exactly (zero scratch), FETCH 32.8 MB, 82 us.
// grid (8, 128): block = 128 q-rows of one (b,h); wave = 32 q-rows (2 groups of 16).
__global__ __launch_bounds__(256) void attn_kernel(
    const bf16* __restrict__ Q, const bf16* __restrict__ K, const bf16* __restrict__ VtG,
    const unsigned long long* __restrict__ mb, bf16* __restrict__ AO)
{
    __shared__ alignas(16) bf16 Ksm[2*64*64];   // dbuf [krow][d], 16B-chunk XOR-swizzled
    __shared__ alignas(16) bf16 Vsm[2*64*64];   // dbuf [d][k-permuted], same swizzle

    const int tid = threadIdx.x, l = tid & 63, w = tid >> 6;
    const int quad = l >> 4, l15 = l & 15;

    // XCD swizzle: flat id f lands on XCD f%8 (round-robin dispatch). Remap so each
    // XCD owns 16 complete (b,h) groups incl. all 8 q-tiles (1024 % 8 == 0, bijective).
    const int fid = blockIdx.y * 8 + blockIdx.x;
    const int xcd = fid & 7, idx = fid >> 3;
    const int bh  = xcd * 16 + (idx >> 3);
    const int qt  = idx & 7;
    const int b = bh >> 4, h = bh & 15;
    const int wrow = qt*128 + w*32;
    const size_t rowbase = (size_t)b * S_;

    bf16x8 qa[2][2];
    #pragma unroll
    for (int g = 0; g < 2; g++) {
        const bf16* qp = Q + (rowbase + wrow + g*16 + l15)*DM + h*DEP + quad*8;
        qa[g][0] = *(const bf16x8*)qp;
        qa[g][1] = *(const bf16x8*)(qp + 32);
    }
    const bf16* kgbase = K + rowbase*DM + h*DEP;
    const bf16* vgbase = VtG + (size_t)(b*16 + h)*64*S_;
    const unsigned long long* mbase[2];
    #pragma unroll
    for (int g = 0; g < 2; g++)
        mbase[g] = mb + ((size_t)h*S_ + wrow + g*16 + l15) * 16;   // u64 per 64-k tile, q = l15

    // per-lane mask bit positions (iteration-invariant)
    uint32_t bmr[4];
    #pragma unroll
    for (int r = 0; r < 4; r++) bmr[r] = 1u << (quad*4 + r);

    bf16x4 onesv;
    #pragma unroll
    for (int r = 0; r < 4; r++) onesv[r] = (bf16)1.0f;

    f32x4 oT[2][4];           // O^T: [d = dt*16 + quad*4 + r][q = l15]
    f32x4 lacc[2];            // ones-row mfma accumulator: all entries == sum_k P[k][q]
    #pragma unroll
    for (int g = 0; g < 2; g++) {
        lacc[g] = f32x4{0.f,0.f,0.f,0.f};
        #pragma unroll
        for (int dt = 0; dt < 4; dt++) oT[g][dt] = f32x4{0.f,0.f,0.f,0.f};
    }

    // staging geometry: tile = 64 rows x 8 chunks of 16B (512 chunks). Per gld_lds
    // issue q, wave w covers LDS chunks [q*256+w*64, +64): lane l -> row q*32+w*8+(l>>3),
    // linear slot l&7. Swizzle: LDS slot s of row r holds GLOBAL chunk s^(r&7), so the
    // source chunk is pre-permuted: gch = (l&7) ^ (l>>3).
    const int srow8 = l >> 3;
    const int gch   = (l & 7) ^ srow8;

    // stage tile 0 into buffer 0
    #pragma unroll
    for (int q = 0; q < 2; q++) {
        const int row = q*32 + w*8 + srow8;
        gld_lds16(kgbase + (size_t)row*DM + gch*8, Ksm + (q*256 + w*64)*8);
        gld_lds16(vgbase + (size_t)row*S_ + gch*8, Vsm + (q*256 + w*64)*8);
    }

    const int rsw = l15 & 7;   // read-side swizzle key (row&7 for all read rows)

    for (int it = 0; it < 16; it++) {
        // Single barrier: implicit vmcnt(0) drains tile-`it` gld_lds writes AND
        // guarantees everyone finished reading buf[nxt] (read during it-1).
        __syncthreads();
        const int cur = (it & 1) * 4096, nxt = cur ^ 4096;
        const bf16* Kc = Ksm + cur;
        const bf16* Vc = Vsm + cur;

        // current-iter mask (first use is after kf reads + QK mfmas: latency covered)
        uint32_t cm[2][2];
        #pragma unroll
        for (int g = 0; g < 2; g++) {
            const unsigned long long mw = mbase[g][it];
            cm[g][0] = (uint32_t)mw; cm[g][1] = (uint32_t)(mw >> 32);
        }

        if (it + 1 < 16) {
            // prefetch tile it+1 straight into the other LDS buffer; drains at next barrier
            #pragma unroll
            for (int q = 0; q < 2; q++) {
                const int row = q*32 + w*8 + srow8;
                gld_lds16(kgbase + (size_t)((it+1)*64 + row)*DM + gch*8,
                          Ksm + nxt + (q*256 + w*64)*8);
                gld_lds16(vgbase + (size_t)row*S_ + (it+1)*64 + gch*8,
                          Vsm + nxt + (q*256 + w*64)*8);
            }
        }

        #pragma unroll
        for (int sub = 0; sub < 2; sub++) {
            bf16x8 kf[2][2];
            bf16x8 va8[4];
            #pragma unroll
            for (int h2 = 0; h2 < 2; h2++) {
                const int krow = sub*32 + h2*16 + l15;
                kf[h2][0] = *(const bf16x8*)(Kc + krow*64 + ((quad    ) ^ rsw)*8);
                kf[h2][1] = *(const bf16x8*)(Kc + krow*64 + ((quad + 4) ^ rsw)*8);
            }
            // k-permuted V: chunk (sub*4+quad) of row d holds [h2=0: r0..3 | h2=1: r0..3]
            #pragma unroll
            for (int dt = 0; dt < 4; dt++)
                va8[dt] = *(const bf16x8*)(Vc + (dt*16 + l15)*64 + ((sub*4 + quad) ^ rsw)*8);

            #pragma unroll
            for (int g = 0; g < 2; g++) {
                // S^T tiles: D[k_local = quad*4+r][q = l15]
                f32x4 st[2];
                __builtin_amdgcn_s_setprio(1);
                #pragma unroll
                for (int h2 = 0; h2 < 2; h2++) {
                    f32x4 z = {0.f,0.f,0.f,0.f};
                    z = __builtin_amdgcn_mfma_f32_16x16x32_bf16(kf[h2][0], qa[g][0], z, 0, 0, 0);
                    z = __builtin_amdgcn_mfma_f32_16x16x32_bf16(kf[h2][1], qa[g][1], z, 0, 0, 0);
                    st[h2] = z;
                }
                __builtin_amdgcn_s_setprio(0);
                const uint32_t msk = cm[g][sub];
                bf16x4 pb[2];
                #pragma unroll
                for (int h2 = 0; h2 < 2; h2++) {
                    const uint32_t mh = msk >> (h2 * 16);   // h2=0 is free
                    #pragma unroll
                    for (int r = 0; r < 4; r++) {
                        const float e = __builtin_amdgcn_exp2f(st[h2][r]);  // scale pre-folded into Q
                        const float pv = (mh & bmr[r]) ? e : 0.f;
                        pb[h2][r] = (bf16)pv;
                    }
                }
                __builtin_amdgcn_s_setprio(1);
                #pragma unroll
                for (int h2 = 0; h2 < 2; h2++) {
                    lacc[g] = mfma16(onesv, pb[h2], lacc[g]);   // denominator on the matrix pipe
                    #pragma unroll
                    for (int dt = 0; dt < 4; dt++) {
                        // zero-cost subregister halves of va8 (NO element-wise array build)
                        const bf16x4 vh = h2
                            ? __builtin_shufflevector(va8[dt], va8[dt], 4, 5, 6, 7)
                            : __builtin_shufflevector(va8[dt], va8[dt], 0, 1, 2, 3);
                        oT[g][dt] = mfma16(vh, pb[h2], oT[g][dt]);
                    }
                }
                __builtin_amdgcn_s_setprio(0);
            }
        }
    }

    #pragma unroll
    for (int g = 0; g < 2; g++) {
        const float inv = 1.0f / lacc[g][0];   // every lane holds the full column sum
        bf16* aor = AO + (rowbase + wrow + g*16 + l15)*DM + h*DEP;
        #pragma unroll
        for (int dt = 0; dt < 4; dt++) {
            bf16x4 ov;
            #pragma unroll
            for (int r = 0; r < 4; r++) ov[r] = (bf16)(oT[g][dt][r] * inv);
            *(bf16x4*)(aor + dt*16 + quad*4) = ov;
        }
    }
}

// ---------------------------------------------------------------- dense + residual (in-place R)
// 64x128 tile, grid (128,8). v10: same single-barrier dbuf as gemm_core.
// LDS: A 2x4KB + B 2x8KB = 24 KB.
__global__ __launch_bounds__(256) void dense_kernel(
    const bf16* __restrict__ AOin, const bf16* __restrict__ dT,
    const bf16* __restrict__ db, bf16* __restrict__ R)
{
    __shared__ alignas(16) bf16 Asm[2*64*32];
    __shared__ alignas(16) bf16 Bsm[2*128*32];
    const int m0 = blockIdx.x * 64, n0 = blockIdx.y * 128;
    const int tid = threadIdx.x, l = tid & 63, w = tid >> 6;
    const int wm = w >> 1, wn = w & 1, quad = l >> 4, l15 = l & 15;

    f32x4 acc[2][4];
    #pragma unroll
    for (int i = 0; i < 2; i++)
        #pragma unroll
        for (int j = 0; j < 4; j++) acc[i][j] = f32x4{0.f, 0.f, 0.f, 0.f};

    const int arow = tid >> 2, ach = tid & 3;    // A: 64 rows x 4 chunks, one per thread
    // prologue: stage tile 0 into half 0
    gld_lds16(AOin + (size_t)(m0 + arow)*DM + ach*8, Asm + (w*64)*8);
    #pragma unroll
    for (int qq = 0; qq < 2; qq++) {
        const int row = qq*64 + arow;
        gld_lds16(dT + (size_t)(n0 + row)*DM + ach*8, Bsm + (qq*256 + w*64)*8);
    }

    for (int it = 0; it < 32; it++) {
        __syncthreads();
        const int curA = (it & 1) * 2048, nxtA = curA ^ 2048;
        const int curB = (it & 1) * 4096, nxtB = curB ^ 4096;
        if (it + 1 < 32) {
            const int k1 = (it + 1) * 32;
            gld_lds16(AOin + (size_t)(m0 + arow)*DM + k1 + ach*8, Asm + nxtA + (w*64)*8);
            #pragma unroll
            for (int qq = 0; qq < 2; qq++) {
                const int row = qq*64 + arow;
                gld_lds16(dT + (size_t)(n0 + row)*DM + k1 + ach*8, Bsm + nxtB + (qq*256 + w*64)*8);
            }
        }
        bf16x8 af[2], bfv[4];
        #pragma unroll
        for (int i = 0; i < 2; i++)
            af[i] = *(const bf16x8*)(Asm + curA + (wm*32 + i*16 + l15)*32 + quad*8);
        #pragma unroll
        for (int j = 0; j < 4; j++)
            bfv[j] = *(const bf16x8*)(Bsm + curB + (wn*64 + j*16 + l15)*32 + quad*8);
        #pragma unroll
        for (int i = 0; i < 2; i++)
            #pragma unroll
            for (int j = 0; j < 4; j++)
                acc[i][j] = __builtin_amdgcn_mfma_f32_16x16x32_bf16(af[i], bfv[j], acc[i][j], 0, 0, 0);
    }

    #pragma unroll
    for (int j = 0; j < 4; j++) {
        const int col = n0 + wn*64 + j*16 + l15;
        const float bv = (float)db[col];
        #pragma unroll
        for (int i = 0; i < 2; i++) {
            const int rb = m0 + wm*32 + i*16 + quad*4;
            #pragma unroll
            for (int r = 0; r < 4; r++) {
                const size_t idx = (size_t)(rb + r)*DM + col;
                R[idx] = (bf16)((float)R[idx] + acc[i][j][r] + bv);
            }
        }
    }
}

// ---------------------------------------------------------------- LayerNorm -> out (bf16 or f32)
__global__ __launch_bounds__(256) void ln_kernel(
    const bf16* __restrict__ R, const bf16* __restrict__ small,
    void* __restrict__ out, const int* __restrict__ flag)
{
    const int isb = *flag;
    __shared__ float red[8];
    const int row = blockIdx.x, tid = threadIdx.x;
    const bf16x4 rv = *(const bf16x4*)(R + (size_t)row*DM + tid*4);
    const float vx = (float)rv[0], vy = (float)rv[1], vz = (float)rv[2], vw = (float)rv[3];
    float s = vx + vy + vz + vw;
    #pragma unroll
    for (int m = 1; m < 64; m <<= 1) s += __shfl_xor(s, m);
    const int w = tid >> 6;
    if ((tid & 63) == 0) red[w] = s;
    __syncthreads();
    const float mu = (red[0] + red[1] + red[2] + red[3]) * (1.0f/DM);
    const float dx = vx - mu, dy = vy - mu, dz = vz - mu, dw = vw - mu;
    float q = dx*dx + dy*dy + dz*dz + dw*dw;
    #pragma unroll
    for (int m = 1; m < 64; m <<= 1) q += __shfl_xor(q, m);
    if ((tid & 63) == 0) red[4 + w] = q;
    __syncthreads();
    const float var = (red[4] + red[5] + red[6] + red[7]) * (1.0f/DM);
    const float rstd = rsqrtf(var + 1e-5f);
    const int col = tid * 4;
    const bf16x4 gv = *(const bf16x4*)(small + 4*1024 + col);
    const bf16x4 bv = *(const bf16x4*)(small + 5*1024 + col);
    const float o0 = dx*rstd*(float)gv[0] + (float)bv[0];
    const float o1 = dy*rstd*(float)gv[1] + (float)bv[1];
    const float o2 = dz*rstd*(float)gv[2] + (float)bv[2];
    const float o3 = dw*rstd*(float)gv[3] + (float)bv[3];
    if (isb) {
        bf16x4 ov; ov[0] = (bf16)o0; ov[1] = (bf16)o1; ov[2] = (bf16)o2; ov[3] = (bf16)o3;
        *(bf16x4*)((bf16*)out + (size_t)row*DM + col) = ov;
    } else {
        float4 ov = {o0, o1, o2, o3};
        *(float4*)((float*)out + (size_t)row*DM + col) = ov;
    }
}

// ---------------------------------------------------------------- launch
extern "C" void kernel_launch(void* const* d_in, const int* in_sizes, int n_in,
                              void* d_out, int out_size, void* d_ws, size_t ws_size,
                              hipStream_t stream) {
    const int* mask = (const int*)d_in[1];

    char* ws = (char*)d_ws;
    bf16* wqT   = (bf16*)(ws);
    bf16* wkT   = (bf16*)(ws + ((size_t)1 << 20));
    bf16* wvT   = (bf16*)(ws + ((size_t)2 << 20));
    bf16* resT  = (bf16*)(ws + ((size_t)3 << 20));
    bf16* dT    = (bf16*)(ws + ((size_t)4 << 20));   // 2 MB
    bf16* small = (bf16*)(ws + ((size_t)6 << 20));   // 12 KB
    int*  flag  = (int*) (ws + ((size_t)6 << 20) + 16384);
    unsigned long long* mbits = (unsigned long long*)(ws + ((size_t)7 << 20)); // 2 MB
    bf16* Qb    = (bf16*)(ws + ((size_t)9  << 20));  // 16 MB (also AO)
    bf16* Kb    = (bf16*)(ws + ((size_t)25 << 20));  // 16 MB
    bf16* VtG   = (bf16*)(ws + ((size_t)41 << 20));  // 16 MB, V transposed [bh][d][s-perm]
    bf16* R     = (bf16*)(ws + ((size_t)57 << 20));  // 16 MB; total 73 MB
    bf16* xc    = (bf16*)d_out;                      // dead until ln_kernel

    detect_kernel<<<1, 64, 0, stream>>>((const uint16_t*)d_in[0], flag);
    transpose_kernel<<<dim3(32, 16, 6), dim3(32, 8), 0, stream>>>(
        d_in[2], d_in[4], d_in[6], d_in[10], d_in[8],
        wqT, wkT, wvT, resT, dT, flag);
    xconv_kernel<<<4096, 256, 0, stream>>>(d_in[0], xc, flag);
    smallconv_kernel<<<6, 256, 0, stream>>>(
        d_in[3], d_in[5], d_in[7], d_in[9], d_in[11], d_in[12], small, flag);
    maskpack_kernel<<<1024, 256, 0, stream>>>(mask, mbits);
    proj_kernel<<<dim3(64, 32), 256, 0, stream>>>(
        xc, wqT, wkT, wvT, resT, small, Qb, Kb, VtG, R);
    attn_kernel<<<dim3(8, 128), 256, 0, stream>>>(Qb, Kb, VtG, mbits, Qb /*AO aliases Q*/);
    dense_kernel<<<dim3(128, 8), 256, 0, stream>>>(Qb, dT, small + 3*1024, R);
    ln_kernel<<<8192, 256, 0, stream>>>(R, small, d_out, flag);
}

// Round 8
// 332.061 us; speedup vs baseline: 1.2353x; 1.0319x over previous
//
#include <hip/hip_runtime.h>
#include <stdint.h>

#define B_ 8
#define S_ 1024
#define IN_DIM 512
#define DM 1024
#define H_ 16
#define DEP 64

typedef __bf16 bf16;
typedef __attribute__((ext_vector_type(8))) __bf16 bf16x8;
typedef __attribute__((ext_vector_type(4))) __bf16 bf16x4;
typedef __attribute__((ext_vector_type(4))) short short4v;
typedef __attribute__((ext_vector_type(4))) float f32x4;

// mfma 16x16x16 bf16: prefer gfx950-style name, fall back to CDNA2 _1k name.
#if defined(__has_builtin)
#if __has_builtin(__builtin_amdgcn_mfma_f32_16x16x16_bf16)
#define HAVE_NEW16 1
#endif
#endif
static __device__ __forceinline__ f32x4 mfma16(bf16x4 a, bf16x4 b, f32x4 c) {
#ifdef HAVE_NEW16
    return __builtin_amdgcn_mfma_f32_16x16x16_bf16(a, b, c, 0, 0, 0);
#else
    union { bf16x4 h; short4v s; } ua, ub;
    ua.h = a; ub.h = b;
    return __builtin_amdgcn_mfma_f32_16x16x16bf16_1k(ua.s, ub.s, c, 0, 0, 0);
#endif
}

// ---------------------------------------------------------------- async copy
static __device__ __forceinline__ void gld_lds16(const void* g, void* l) {
    __builtin_amdgcn_global_load_lds(
        (const __attribute__((address_space(1))) uint32_t*)g,
        (__attribute__((address_space(3))) uint32_t*)l, 16, 0, 0);
}

static __device__ __forceinline__ float ldin(const void* p, size_t i, int isb) {
    return isb ? (float)((const bf16*)p)[i] : ((const float*)p)[i];
}

// ---------------------------------------------------------------- fused prep
// v11: detect/transpose/xconv/smallconv/maskpack were 5 SERIAL launches (~20 us of
// work). One kernel, one launch; block ranges partition the work and all run
// concurrently. Each block re-derives isb from xraw[0:512] (1 KB, L2-hot after the
// first block, ~free) - removes the flag cross-launch dependency. maskpack blocks
// come FIRST (longest pole, ~11 us) so dispatch starts them immediately.
// layout: [0,1024) maskpack | [1024,5120) xconv | [5120,8192) transpose | [8192,8198) small
__global__ __launch_bounds__(256) void prep_kernel(
    const uint16_t* __restrict__ xraw, const void* __restrict__ x,
    const void* __restrict__ wq, const void* __restrict__ wk, const void* __restrict__ wv,
    const void* __restrict__ res, const void* __restrict__ dense,
    const int* __restrict__ mask,
    bf16* __restrict__ wqT, bf16* __restrict__ wkT, bf16* __restrict__ wvT,
    bf16* __restrict__ resT, bf16* __restrict__ denseT,
    const void* b0, const void* b1, const void* b2, const void* b3,
    const void* b4, const void* b5, bf16* __restrict__ small,
    bf16* __restrict__ xc, unsigned long long* __restrict__ mb, int* __restrict__ flag)
{
    __shared__ int s_isb;
    __shared__ bf16 tile[32][33];
    const int tid = threadIdx.x;

    // per-block dtype detect (threads 0-63 = one full wave)
    if (tid < 64) {
        int sane = 0;
        #pragma unroll
        for (int j = 0; j < 8; j++) {
            const uint16_t u = xraw[tid * 8 + j];
            const int e = (u >> 7) & 0xff;
            sane += ((u & 0x7fff) == 0 || (e >= 100 && e <= 140)) ? 1 : 0;
        }
        #pragma unroll
        for (int m = 1; m < 64; m <<= 1) sane += __shfl_xor(sane, m);
        if (tid == 0) s_isb = (sane >= 450) ? 1 : 0;
    }
    __syncthreads();
    const int isb = s_isb;
    const int bid = blockIdx.x;
    if (bid == 0 && tid == 0) *flag = isb;   // for ln_kernel (later launch, stream-ordered)

    if (bid < 1024) {
        // ---- maskpack: 64 MB int32 -> 2 MB bitmask
        const int w = tid >> 6, lane = tid & 63;
        const int gw = bid * 4 + w;              // 4096 waves
        for (int c = gw; c < 262144; c += 4096) {
            const int v = mask[(size_t)c * 64 + lane];
            const unsigned long long bits = __ballot(v != 0);
            if (lane == 0) mb[c] = bits;
        }
    } else if (bid < 5120) {
        // ---- xconv: x -> bf16, vectorized
        const size_t i = ((size_t)(bid - 1024) * 256 + tid) * 4;
        if (isb) {
            *(bf16x4*)(xc + i) = *(const bf16x4*)((const bf16*)x + i);
        } else {
            const float4 v = *(const float4*)((const float*)x + i);
            bf16x4 o; o[0] = (bf16)v.x; o[1] = (bf16)v.y; o[2] = (bf16)v.z; o[3] = (bf16)v.w;
            *(bf16x4*)(xc + i) = o;
        }
    } else if (bid < 8192) {
        // ---- weight transpose -> bf16 [N][K]
        const int t = bid - 5120;
        const int z = t >> 9, rem = t & 511;
        const void* src; bf16* dst; int kb, kd;
        if (z == 0)      { src = wq;    dst = wqT;    kb = 0;   kd = 512;  }
        else if (z == 1) { src = wk;    dst = wkT;    kb = 0;   kd = 512;  }
        else if (z == 2) { src = wv;    dst = wvT;    kb = 0;   kd = 512;  }
        else if (z == 3) { src = res;   dst = resT;   kb = 0;   kd = 512;  }
        else if (z == 4) { src = dense; dst = denseT; kb = 0;   kd = 1024; }
        else             { src = dense; dst = denseT; kb = 512; kd = 1024; }
        const int n0 = (rem & 31) * 32, k0 = (rem >> 5) * 32;
        const int tx = tid & 31, ty = tid >> 5;
        #pragma unroll
        for (int r = 0; r < 4; r++)
            tile[ty + r*8][tx] = (bf16)ldin(src, (size_t)(kb + k0 + ty + r*8) * DM + n0 + tx, isb);
        __syncthreads();
        #pragma unroll
        for (int r = 0; r < 4; r++)
            dst[(size_t)(n0 + ty + r*8) * kd + kb + k0 + tx] = tile[tx][ty + r*8];
    } else {
        // ---- small vectors -> bf16: [wq_b, wk_b, wv_b, dense_b, ln_g, ln_b]
        const int s6 = bid - 8192;
        const void* srcs[6] = {b0, b1, b2, b3, b4, b5};
        const void* s = srcs[s6];
        for (int i = tid; i < 1024; i += 256)
            small[s6 * 1024 + i] = (bf16)ldin(s, i, isb);
    }
}

// ---------------------------------------------------------------- GEMM core 128x128, dbuf (r7, kept)
template<int KDIM>
static __device__ __forceinline__ void gemm_core(
    const bf16* __restrict__ A, const bf16* __restrict__ BT,
    int m0, int n0, bf16* Asm, bf16* Bsm, f32x4 acc[4][4])
{
    const int tid = threadIdx.x, l = tid & 63, w = tid >> 6;
    const int wm = w >> 1, wn = w & 1, quad = l >> 4, l15 = l & 15;
    #pragma unroll
    for (int i = 0; i < 4; i++)
        #pragma unroll
        for (int j = 0; j < 4; j++) acc[i][j] = f32x4{0.f, 0.f, 0.f, 0.f};

    constexpr int NIT = KDIM / 32;
    const int srow = tid >> 2, sch = tid & 3;

    #pragma unroll
    for (int qq = 0; qq < 2; qq++) {
        const int row = qq*64 + srow;
        gld_lds16(A  + (size_t)(m0 + row)*KDIM + sch*8, Asm + (qq*256 + w*64)*8);
        gld_lds16(BT + (size_t)(n0 + row)*KDIM + sch*8, Bsm + (qq*256 + w*64)*8);
    }

    for (int it = 0; it < NIT; it++) {
        __syncthreads();
        const int cur = (it & 1) * 4096;
        const int nxt = cur ^ 4096;
        if (it + 1 < NIT) {
            const int k1 = (it + 1) * 32;
            #pragma unroll
            for (int qq = 0; qq < 2; qq++) {
                const int row = qq*64 + srow;
                gld_lds16(A  + (size_t)(m0 + row)*KDIM + k1 + sch*8, Asm + nxt + (qq*256 + w*64)*8);
                gld_lds16(BT + (size_t)(n0 + row)*KDIM + k1 + sch*8, Bsm + nxt + (qq*256 + w*64)*8);
            }
        }
        bf16x8 af[4], bfv[4];
        #pragma unroll
        for (int i = 0; i < 4; i++)
            af[i] = *(const bf16x8*)(Asm + cur + (wm*64 + i*16 + l15)*32 + quad*8);
        #pragma unroll
        for (int j = 0; j < 4; j++)
            bfv[j] = *(const bf16x8*)(Bsm + cur + (wn*64 + j*16 + l15)*32 + quad*8);
        #pragma unroll
        for (int i = 0; i < 4; i++)
            #pragma unroll
            for (int j = 0; j < 4; j++)
                acc[i][j] = __builtin_amdgcn_mfma_f32_16x16x32_bf16(af[i], bfv[j], acc[i][j], 0, 0, 0);
    }
}

// ---------------------------------------------------------------- QKV + residual projection
// grid (64, 32). sel: 0=Q (scaled 0.125*log2(e)), 1=K, 2=V (transposed, k-permuted), 3=residual.
#define EPI_P 132
__global__ __launch_bounds__(256) void proj_kernel(
    const bf16* __restrict__ x,
    const bf16* __restrict__ wqT, const bf16* __restrict__ wkT,
    const bf16* __restrict__ wvT, const bf16* __restrict__ resT,
    const bf16* __restrict__ small,
    bf16* __restrict__ Q, bf16* __restrict__ K, bf16* __restrict__ VtG, bf16* __restrict__ R)
{
    __shared__ alignas(16) char smem[32768];   // dbuf staging | V-epilogue (16896) aliases
    bf16* Asm = (bf16*)smem;
    bf16* Bsm = (bf16*)(smem + 16384);
    bf16* epi = (bf16*)smem;                   // [64 cols][EPI_P] rows-pitch

    const int m0 = blockIdx.x * 128;
    const int ng = blockIdx.y * 128;
    const int sel = ng >> 10, n0 = ng & 1023;
    const bf16* BT; const bf16* bias = nullptr;
    if (sel == 0)      { BT = wqT; bias = small;        }
    else if (sel == 1) { BT = wkT; bias = small + 1024; }
    else if (sel == 2) { BT = wvT; bias = small + 2048; }
    else               { BT = resT; }

    f32x4 acc[4][4];
    gemm_core<IN_DIM>(x, BT, m0, n0, Asm, Bsm, acc);

    const int tid = threadIdx.x, l = tid & 63, w = tid >> 6;
    const int wm = w >> 1, wn = w & 1, quad = l >> 4, l15 = l & 15;

    if (sel == 2) {
        // V: stage [col][row] in LDS, emit transposed VtG[(b*16+h)*64 + d][s'] coalesced.
        // s' is k-PERMUTED within each 32-block (p = quad*8 + h2*4 + r for
        // kl = h2*16 + quad*4 + r): attn fetches both h2 fragments with ONE ds_read_b128.
        const int bb = m0 >> 10, srow0 = m0 & 1023;
        #pragma unroll
        for (int hf = 0; hf < 2; hf++) {
            __syncthreads();
            if (wn == hf) {
                #pragma unroll
                for (int j = 0; j < 4; j++) {
                    const int cl = j*16 + l15;
                    const float bv = (float)bias[n0 + hf*64 + cl];
                    #pragma unroll
                    for (int i = 0; i < 4; i++) {
                        const int rho = wm*64 + i*16 + quad*4;
                        #pragma unroll
                        for (int r = 0; r < 4; r++)
                            epi[cl*EPI_P + rho + r] = (bf16)(acc[i][j][r] + bv);
                    }
                }
            }
            __syncthreads();
            const int hh = (n0 >> 6) + hf;
            const int sc = tid & 15;
            #pragma unroll
            for (int pass = 0; pass < 4; pass++) {
                const int dl = (tid >> 4) + pass*16;
                bf16x8 v;
                #pragma unroll
                for (int k = 0; k < 8; k++) {
                    const int pl = (sc & 3)*8 + k;                                  // pos in 32-block
                    const int kl = ((pl & 4) << 2) | ((pl & 24) >> 1) | (pl & 3);   // source pos
                    v[k] = epi[dl*EPI_P + (sc >> 2)*32 + kl];
                }
                *(bf16x8*)(VtG + ((size_t)(bb*16 + hh)*64 + dl)*S_ + srow0 + sc*8) = v;
            }
        }
        return;
    }

    #pragma unroll
    for (int j = 0; j < 4; j++) {
        const int col = n0 + wn*64 + j*16 + l15;
        const float bv = (sel < 3) ? (float)bias[col] : 0.f;
        #pragma unroll
        for (int i = 0; i < 4; i++) {
            const int rb = m0 + wm*64 + i*16 + quad*4;
            #pragma unroll
            for (int r = 0; r < 4; r++) {
                const float v = acc[i][j][r] + bv;
                // 0.125 * log2(e): scores in base-2 domain -> attn uses raw v_exp_f32.
                if (sel == 0)      Q[(size_t)(rb + r)*DM + col] = (bf16)(v * 0.18033688f);
                else if (sel == 1) K[(size_t)(rb + r)*DM + col] = (bf16)v;
                else               R[(size_t)(rb + r)*DM + col] = (bf16)v;
            }
        }
    }
}

// ---------------------------------------------------------------- flash attention v11
// vs v9 (r6/r7-verified: VGPR 88, zero scratch, 81.4 us): restore the 1-iter mask
// prefetch (r2 dropped it under the now-removed 64-VGPR cap). The per-iter 2x8B L2
// mask loads were used within ~40 cy of issue (only QK mfmas between) - ~150 cy
// exposed. Prefetching 1 iter ahead costs 4 VGPRs (88 -> ~92, no occupancy change).
// grid (8, 128): block = 128 q-rows of one (b,h); wave = 32 q-rows (2 groups of 16).
__global__ __launch_bounds__(256) void attn_kernel(
    const bf16* __restrict__ Q, const bf16* __restrict__ K, const bf16* __restrict__ VtG,
    const unsigned long long* __restrict__ mb, bf16* __restrict__ AO)
{
    __shared__ alignas(16) bf16 Ksm[2*64*64];   // dbuf [krow][d], 16B-chunk XOR-swizzled
    __shared__ alignas(16) bf16 Vsm[2*64*64];   // dbuf [d][k-permuted], same swizzle

    const int tid = threadIdx.x, l = tid & 63, w = tid >> 6;
    const int quad = l >> 4, l15 = l & 15;

    // XCD swizzle: each XCD owns 16 complete (b,h) groups incl. all 8 q-tiles.
    const int fid = blockIdx.y * 8 + blockIdx.x;
    const int xcd = fid & 7, idx = fid >> 3;
    const int bh  = xcd * 16 + (idx >> 3);
    const int qt  = idx & 7;
    const int b = bh >> 4, h = bh & 15;
    const int wrow = qt*128 + w*32;
    const size_t rowbase = (size_t)b * S_;

    bf16x8 qa[2][2];
    #pragma unroll
    for (int g = 0; g < 2; g++) {
        const bf16* qp = Q + (rowbase + wrow + g*16 + l15)*DM + h*DEP + quad*8;
        qa[g][0] = *(const bf16x8*)qp;
        qa[g][1] = *(const bf16x8*)(qp + 32);
    }
    const bf16* kgbase = K + rowbase*DM + h*DEP;
    const bf16* vgbase = VtG + (size_t)(b*16 + h)*64*S_;
    const unsigned long long* mbase[2];
    #pragma unroll
    for (int g = 0; g < 2; g++)
        mbase[g] = mb + ((size_t)h*S_ + wrow + g*16 + l15) * 16;   // u64 per 64-k tile, q = l15

    uint32_t bmr[4];
    #pragma unroll
    for (int r = 0; r < 4; r++) bmr[r] = 1u << (quad*4 + r);

    bf16x4 onesv;
    #pragma unroll
    for (int r = 0; r < 4; r++) onesv[r] = (bf16)1.0f;

    f32x4 oT[2][4];           // O^T: [d = dt*16 + quad*4 + r][q = l15]
    f32x4 lacc[2];            // ones-row mfma accumulator
    #pragma unroll
    for (int g = 0; g < 2; g++) {
        lacc[g] = f32x4{0.f,0.f,0.f,0.f};
        #pragma unroll
        for (int dt = 0; dt < 4; dt++) oT[g][dt] = f32x4{0.f,0.f,0.f,0.f};
    }

    const int srow8 = l >> 3;
    const int gch   = (l & 7) ^ srow8;   // pre-swizzled source chunk

    // stage tile 0 into buffer 0
    #pragma unroll
    for (int q = 0; q < 2; q++) {
        const int row = q*32 + w*8 + srow8;
        gld_lds16(kgbase + (size_t)row*DM + gch*8, Ksm + (q*256 + w*64)*8);
        gld_lds16(vgbase + (size_t)row*S_ + gch*8, Vsm + (q*256 + w*64)*8);
    }
    // prefetch mask words for tile 0
    uint32_t mlo[2], mhi[2];
    #pragma unroll
    for (int g = 0; g < 2; g++) {
        const unsigned long long mw = mbase[g][0];
        mlo[g] = (uint32_t)mw; mhi[g] = (uint32_t)(mw >> 32);
    }

    const int rsw = l15 & 7;   // read-side swizzle key

    for (int it = 0; it < 16; it++) {
        __syncthreads();       // drains tile-it gld_lds; protects nxt buffer
        const int cur = (it & 1) * 4096, nxt = cur ^ 4096;
        const bf16* Kc = Ksm + cur;
        const bf16* Vc = Vsm + cur;

        const uint32_t cmlo[2] = {mlo[0], mlo[1]}, cmhi[2] = {mhi[0], mhi[1]};
        if (it + 1 < 16) {
            // prefetch tile it+1 (LDS) + its mask words (regs); both consumed next iter
            #pragma unroll
            for (int q = 0; q < 2; q++) {
                const int row = q*32 + w*8 + srow8;
                gld_lds16(kgbase + (size_t)((it+1)*64 + row)*DM + gch*8,
                          Ksm + nxt + (q*256 + w*64)*8);
                gld_lds16(vgbase + (size_t)row*S_ + (it+1)*64 + gch*8,
                          Vsm + nxt + (q*256 + w*64)*8);
            }
            #pragma unroll
            for (int g = 0; g < 2; g++) {
                const unsigned long long mw = mbase[g][it + 1];
                mlo[g] = (uint32_t)mw; mhi[g] = (uint32_t)(mw >> 32);
            }
        }

        #pragma unroll
        for (int sub = 0; sub < 2; sub++) {
            bf16x8 kf[2][2];
            bf16x8 va8[4];
            #pragma unroll
            for (int h2 = 0; h2 < 2; h2++) {
                const int krow = sub*32 + h2*16 + l15;
                kf[h2][0] = *(const bf16x8*)(Kc + krow*64 + ((quad    ) ^ rsw)*8);
                kf[h2][1] = *(const bf16x8*)(Kc + krow*64 + ((quad + 4) ^ rsw)*8);
            }
            #pragma unroll
            for (int dt = 0; dt < 4; dt++)
                va8[dt] = *(const bf16x8*)(Vc + (dt*16 + l15)*64 + ((sub*4 + quad) ^ rsw)*8);

            #pragma unroll
            for (int g = 0; g < 2; g++) {
                f32x4 st[2];
                __builtin_amdgcn_s_setprio(1);
                #pragma unroll
                for (int h2 = 0; h2 < 2; h2++) {
                    f32x4 z = {0.f,0.f,0.f,0.f};
                    z = __builtin_amdgcn_mfma_f32_16x16x32_bf16(kf[h2][0], qa[g][0], z, 0, 0, 0);
                    z = __builtin_amdgcn_mfma_f32_16x16x32_bf16(kf[h2][1], qa[g][1], z, 0, 0, 0);
                    st[h2] = z;
                }
                __builtin_amdgcn_s_setprio(0);
                const uint32_t msk = sub ? cmhi[g] : cmlo[g];
                bf16x4 pb[2];
                #pragma unroll
                for (int h2 = 0; h2 < 2; h2++) {
                    const uint32_t mh = msk >> (h2 * 16);   // h2=0 is free
                    #pragma unroll
                    for (int r = 0; r < 4; r++) {
                        const float e = __builtin_amdgcn_exp2f(st[h2][r]);
                        const float pv = (mh & bmr[r]) ? e : 0.f;
                        pb[h2][r] = (bf16)pv;
                    }
                }
                __builtin_amdgcn_s_setprio(1);
                #pragma unroll
                for (int h2 = 0; h2 < 2; h2++) {
                    lacc[g] = mfma16(onesv, pb[h2], lacc[g]);
                    #pragma unroll
                    for (int dt = 0; dt < 4; dt++) {
                        const bf16x4 vh = h2
                            ? __builtin_shufflevector(va8[dt], va8[dt], 4, 5, 6, 7)
                            : __builtin_shufflevector(va8[dt], va8[dt], 0, 1, 2, 3);
                        oT[g][dt] = mfma16(vh, pb[h2], oT[g][dt]);
                    }
                }
                __builtin_amdgcn_s_setprio(0);
            }
        }
    }

    #pragma unroll
    for (int g = 0; g < 2; g++) {
        const float inv = 1.0f / lacc[g][0];
        bf16* aor = AO + (rowbase + wrow + g*16 + l15)*DM + h*DEP;
        #pragma unroll
        for (int dt = 0; dt < 4; dt++) {
            bf16x4 ov;
            #pragma unroll
            for (int r = 0; r < 4; r++) ov[r] = (bf16)(oT[g][dt][r] * inv);
            *(bf16x4*)(aor + dt*16 + quad*4) = ov;
        }
    }
}

// ---------------------------------------------------------------- dense + residual (in-place R)
// 64x128 tile, grid (128,8), single-barrier dbuf (r7). LDS 24 KB.
__global__ __launch_bounds__(256) void dense_kernel(
    const bf16* __restrict__ AOin, const bf16* __restrict__ dT,
    const bf16* __restrict__ db, bf16* __restrict__ R)
{
    __shared__ alignas(16) bf16 Asm[2*64*32];
    __shared__ alignas(16) bf16 Bsm[2*128*32];
    const int m0 = blockIdx.x * 64, n0 = blockIdx.y * 128;
    const int tid = threadIdx.x, l = tid & 63, w = tid >> 6;
    const int wm = w >> 1, wn = w & 1, quad = l >> 4, l15 = l & 15;

    f32x4 acc[2][4];
    #pragma unroll
    for (int i = 0; i < 2; i++)
        #pragma unroll
        for (int j = 0; j < 4; j++) acc[i][j] = f32x4{0.f, 0.f, 0.f, 0.f};

    const int arow = tid >> 2, ach = tid & 3;
    gld_lds16(AOin + (size_t)(m0 + arow)*DM + ach*8, Asm + (w*64)*8);
    #pragma unroll
    for (int qq = 0; qq < 2; qq++) {
        const int row = qq*64 + arow;
        gld_lds16(dT + (size_t)(n0 + row)*DM + ach*8, Bsm + (qq*256 + w*64)*8);
    }

    for (int it = 0; it < 32; it++) {
        __syncthreads();
        const int curA = (it & 1) * 2048, nxtA = curA ^ 2048;
        const int curB = (it & 1) * 4096, nxtB = curB ^ 4096;
        if (it + 1 < 32) {
            const int k1 = (it + 1) * 32;
            gld_lds16(AOin + (size_t)(m0 + arow)*DM + k1 + ach*8, Asm + nxtA + (w*64)*8);
            #pragma unroll
            for (int qq = 0; qq < 2; qq++) {
                const int row = qq*64 + arow;
                gld_lds16(dT + (size_t)(n0 + row)*DM + k1 + ach*8, Bsm + nxtB + (qq*256 + w*64)*8);
            }
        }
        bf16x8 af[2], bfv[4];
        #pragma unroll
        for (int i = 0; i < 2; i++)
            af[i] = *(const bf16x8*)(Asm + curA + (wm*32 + i*16 + l15)*32 + quad*8);
        #pragma unroll
        for (int j = 0; j < 4; j++)
            bfv[j] = *(const bf16x8*)(Bsm + curB + (wn*64 + j*16 + l15)*32 + quad*8);
        #pragma unroll
        for (int i = 0; i < 2; i++)
            #pragma unroll
            for (int j = 0; j < 4; j++)
                acc[i][j] = __builtin_amdgcn_mfma_f32_16x16x32_bf16(af[i], bfv[j], acc[i][j], 0, 0, 0);
    }

    #pragma unroll
    for (int j = 0; j < 4; j++) {
        const int col = n0 + wn*64 + j*16 + l15;
        const float bv = (float)db[col];
        #pragma unroll
        for (int i = 0; i < 2; i++) {
            const int rb = m0 + wm*32 + i*16 + quad*4;
            #pragma unroll
            for (int r = 0; r < 4; r++) {
                const size_t idx = (size_t)(rb + r)*DM + col;
                R[idx] = (bf16)((float)R[idx] + acc[i][j][r] + bv);
            }
        }
    }
}

// ---------------------------------------------------------------- LayerNorm (wave-per-row, no LDS)
// v11: one wave owns one full row (16 f32/lane) -> pure shuffle reduce, zero barriers.
// grid 2048 x 256 thr = 4 rows/block.
__global__ __launch_bounds__(256) void ln_kernel(
    const bf16* __restrict__ R, const bf16* __restrict__ small,
    void* __restrict__ out, const int* __restrict__ flag)
{
    const int isb = *flag;
    const int row  = blockIdx.x * 4 + (threadIdx.x >> 6);
    const int lane = threadIdx.x & 63;
    const bf16* rp = R + (size_t)row*DM;

    float v[16];
    float s = 0.f;
    #pragma unroll
    for (int k = 0; k < 4; k++) {
        const bf16x4 rv = *(const bf16x4*)(rp + k*256 + lane*4);
        #pragma unroll
        for (int r = 0; r < 4; r++) { v[k*4+r] = (float)rv[r]; s += v[k*4+r]; }
    }
    #pragma unroll
    for (int m = 1; m < 64; m <<= 1) s += __shfl_xor(s, m);
    const float mu = s * (1.0f/DM);

    float q = 0.f;
    #pragma unroll
    for (int i = 0; i < 16; i++) { v[i] -= mu; q += v[i]*v[i]; }
    #pragma unroll
    for (int m = 1; m < 64; m <<= 1) q += __shfl_xor(q, m);
    const float rstd = rsqrtf(q * (1.0f/DM) + 1e-5f);

    #pragma unroll
    for (int k = 0; k < 4; k++) {
        const int col = k*256 + lane*4;
        const bf16x4 gv = *(const bf16x4*)(small + 4*1024 + col);
        const bf16x4 bv = *(const bf16x4*)(small + 5*1024 + col);
        float o[4];
        #pragma unroll
        for (int r = 0; r < 4; r++) o[r] = v[k*4+r]*rstd*(float)gv[r] + (float)bv[r];
        if (isb) {
            bf16x4 ov;
            #pragma unroll
            for (int r = 0; r < 4; r++) ov[r] = (bf16)o[r];
            *(bf16x4*)((bf16*)out + (size_t)row*DM + col) = ov;
        } else {
            float4 ov = {o[0], o[1], o[2], o[3]};
            *(float4*)((float*)out + (size_t)row*DM + col) = ov;
        }
    }
}

// ---------------------------------------------------------------- launch
extern "C" void kernel_launch(void* const* d_in, const int* in_sizes, int n_in,
                              void* d_out, int out_size, void* d_ws, size_t ws_size,
                              hipStream_t stream) {
    const int* mask = (const int*)d_in[1];

    char* ws = (char*)d_ws;
    bf16* wqT   = (bf16*)(ws);
    bf16* wkT   = (bf16*)(ws + ((size_t)1 << 20));
    bf16* wvT   = (bf16*)(ws + ((size_t)2 << 20));
    bf16* resT  = (bf16*)(ws + ((size_t)3 << 20));
    bf16* dT    = (bf16*)(ws + ((size_t)4 << 20));   // 2 MB
    bf16* small = (bf16*)(ws + ((size_t)6 << 20));   // 12 KB
    int*  flag  = (int*) (ws + ((size_t)6 << 20) + 16384);
    unsigned long long* mbits = (unsigned long long*)(ws + ((size_t)7 << 20)); // 2 MB
    bf16* Qb    = (bf16*)(ws + ((size_t)9  << 20));  // 16 MB (also AO)
    bf16* Kb    = (bf16*)(ws + ((size_t)25 << 20));  // 16 MB
    bf16* VtG   = (bf16*)(ws + ((size_t)41 << 20));  // 16 MB, V transposed [bh][d][s-perm]
    bf16* R     = (bf16*)(ws + ((size_t)57 << 20));  // 16 MB; total 73 MB
    bf16* xc    = (bf16*)d_out;                      // dead until ln_kernel

    prep_kernel<<<8198, 256, 0, stream>>>(
        (const uint16_t*)d_in[0], d_in[0],
        d_in[2], d_in[4], d_in[6], d_in[10], d_in[8],
        mask,
        wqT, wkT, wvT, resT, dT,
        d_in[3], d_in[5], d_in[7], d_in[9], d_in[11], d_in[12], small,
        xc, mbits, flag);
    proj_kernel<<<dim3(64, 32), 256, 0, stream>>>(
        xc, wqT, wkT, wvT, resT, small, Qb, Kb, VtG, R);
    attn_kernel<<<dim3(8, 128), 256, 0, stream>>>(Qb, Kb, VtG, mbits, Qb /*AO aliases Q*/);
    dense_kernel<<<dim3(128, 8), 256, 0, stream>>>(Qb, dT, small + 3*1024, R);
    ln_kernel<<<2048, 256, 0, stream>>>(R, small, d_out, flag);
}